// Round 9
// baseline (325.525 us; speedup 1.0000x reference)
//
#include <hip/hip_runtime.h>
#include <math.h>

#define SEQ    2048
#define DMODEL 768
#define NHEAD  12
#define NEXP   8
#define IDIM   1024
#define ISH    2048
#define KVS    4
#define NE2    10   // 8 routed experts + 2 shared-expert halves
#define ATTN_BLOCKS 1536  // 32 q-tiles * 12 heads * 4 kv-splits
#define CVT_BLOCKS 10752  // (3*786432 + 2*196608)/256 exactly

typedef unsigned short u16;
typedef short s16x8 __attribute__((ext_vector_type(8)));
typedef u16   u16x8 __attribute__((ext_vector_type(8)));
typedef float f32x4 __attribute__((ext_vector_type(4)));

#define MFMA_BF16(a, b, c) __builtin_amdgcn_mfma_f32_16x16x32_bf16((a), (b), (c), 0, 0, 0)

__device__ __forceinline__ void glds16(const void* g, void* l) {
  __builtin_amdgcn_global_load_lds(
      (const __attribute__((address_space(1))) unsigned int*)g,
      (__attribute__((address_space(3))) unsigned int*)l, 16, 0, 0);
}

__device__ __forceinline__ u16 f2b(float f) {  // fp32 -> bf16 RNE
  unsigned int u = __float_as_uint(f);
  unsigned int r = u + 0x7fffu + ((u >> 16) & 1u);
  return (u16)(r >> 16);
}
__device__ __forceinline__ float b2f(u16 v) {
  return __uint_as_float(((unsigned int)v) << 16);
}

// ---------------------------------------------------------------- rmsnorm1 (+ zero counts)
__global__ __launch_bounds__(256) void rmsnorm_kernel(const float* __restrict__ x,
                                                      const float* __restrict__ n1w,
                                                      u16* __restrict__ xnb,
                                                      int* __restrict__ counts) {
  const int tid = threadIdx.x;
  if (blockIdx.x == 0 && tid < 16) counts[tid] = 0;
  const int row = blockIdx.x;
  const float* r = x + (size_t)row * DMODEL;
  float v0 = r[tid], v1 = r[tid + 256], v2 = r[tid + 512];
  float ss = v0 * v0 + v1 * v1 + v2 * v2;
  __shared__ float red[256];
  red[tid] = ss;
  __syncthreads();
  for (int s = 128; s > 0; s >>= 1) {
    if (tid < s) red[tid] += red[tid + s];
    __syncthreads();
  }
  float rms = rsqrtf(red[0] * (1.f / DMODEL) + 1e-5f);
  u16* ob = xnb + (size_t)row * DMODEL;
  ob[tid]       = f2b(v0 * rms * n1w[tid]);
  ob[tid + 256] = f2b(v1 * rms * n1w[tid + 256]);
  ob[tid + 512] = f2b(v2 * rms * n1w[tid + 512]);
}

// ---------------------------------------------------------------- merged: MFMA flash attention
// (blocks [0,ATTN_BLOCKS)) + weight conversion (blocks after). attn = MFMA/LDS-bound,
// cvt = HBM-bound; co-scheduling overlaps the two pipes instead of running serially.
// Qs/Ks: [64][64] XOR-swizzled (key = (row&15)>>1) + glds16 async staging.
__global__ __launch_bounds__(256) void attn_cvt_kernel(
    const u16* __restrict__ xnb, u16* __restrict__ Opart,
    float* __restrict__ Mpart, float* __restrict__ Lpart,
    const float* __restrict__ w1, const float* __restrict__ w3, const float* __restrict__ w2,
    const float* __restrict__ fc1, const float* __restrict__ fc2,
    u16* __restrict__ w1b, u16* __restrict__ w3b, u16* __restrict__ w2b,
    u16* __restrict__ fc1b, u16* __restrict__ fc2b) {
  const int tid = threadIdx.x;
  if (blockIdx.x >= ATTN_BLOCKS) {
    // ---- weight cvt ----
    long i = (long)(blockIdx.x - ATTN_BLOCKS) * 256 + tid;
    const long NW8 = (long)NEXP * IDIM * DMODEL / 8;   // 786432
    const long NF8 = (long)ISH * DMODEL / 8;           // 196608
    const float* s; u16* d; long o;
    if      (i < NW8)             { s = w1;  d = w1b;  o = i; }
    else if (i < 2 * NW8)         { s = w3;  d = w3b;  o = i - NW8; }
    else if (i < 3 * NW8)         { s = w2;  d = w2b;  o = i - 2 * NW8; }
    else if (i < 3 * NW8 + NF8)   { s = fc1; d = fc1b; o = i - 3 * NW8; }
    else                          { s = fc2; d = fc2b; o = i - 3 * NW8 - NF8; }
    float4 a = ((const float4*)s)[2 * o], b = ((const float4*)s)[2 * o + 1];
    u16x8 v;
    v[0] = f2b(a.x); v[1] = f2b(a.y); v[2] = f2b(a.z); v[3] = f2b(a.w);
    v[4] = f2b(b.x); v[5] = f2b(b.y); v[6] = f2b(b.z); v[7] = f2b(b.w);
    ((u16x8*)d)[o] = v;
    return;
  }
  // ---- attention ----
  __shared__ u16 Qs[64][64];   // XOR-swizzled: slot (r, j) holds global chunk j ^ ((r&15)>>1)
  __shared__ u16 Ks[64][64];
  __shared__ u16 Vt[64][72];   // transposed V: [d][k] (reg-written, padded)
  __shared__ u16 Ps[64][72];   // P in A-layout: [q][k]
  const int q0 = (blockIdx.x & 31) * 64;
  const int h = (blockIdx.x >> 5) % NHEAD;
  const int kvs = blockIdx.x / (32 * NHEAD);
  const int lane = tid & 63, w = tid >> 6;
  const int quad = lane >> 4, l15 = lane & 15;
  const size_t hoff = (size_t)h * 64;

  const int lr8 = lane >> 3, b7 = lane & 7;
  // staging source chunks (pre-swizzled): c=0 key = (lr8>>1), c=1 key = 4+(lr8>>1)
  const int sch0 = (b7 ^ (lr8 >> 1)) * 8;
  const int sch1 = (b7 ^ (4 + (lr8 >> 1))) * 8;
  const int rkey = (l15 >> 1) & 7;     // fragment read key
  const int cb0 = (quad ^ rkey) * 8;         // chunk quad
  const int cb1 = ((4 + quad) ^ rkey) * 8;   // chunk 4+quad

  glds16(xnb + (size_t)(q0 + 16 * w + lr8) * DMODEL + hoff + sch0, &Qs[16 * w][0]);
  glds16(xnb + (size_t)(q0 + 16 * w + 8 + lr8) * DMODEL + hoff + sch1, &Qs[16 * w + 8][0]);
  __syncthreads();
  const s16x8 aq0 = *(const s16x8*)&Qs[16 * w + l15][cb0];
  const s16x8 aq1 = *(const s16x8*)&Qs[16 * w + l15][cb1];

  f32x4 o[4] = {};
  float mrow[4], lrow[4];
#pragma unroll
  for (int r = 0; r < 4; r++) { mrow[r] = -INFINITY; lrow[r] = 0.f; }

  const int it0 = kvs * (SEQ / 64 / KVS);
  for (int it = 0; it < SEQ / 64 / KVS; it++) {
    const int k0 = (it0 + it) * 64;
    glds16(xnb + (size_t)(k0 + 16 * w + lr8) * DMODEL + hoff + sch0, &Ks[16 * w][0]);
    glds16(xnb + (size_t)(k0 + 16 * w + 8 + lr8) * DMODEL + hoff + sch1, &Ks[16 * w + 8][0]);
    __syncthreads();

    {
      // transpose K -> Vt; read swizzled Ks (key = rp&7 for both rows 2rp, 2rp+1)
      const int rp = tid & 31, dcc = (tid >> 5) & 7;
      const int tc = (dcc ^ (rp & 7)) * 8;
      u16x8 v0 = *(const u16x8*)&Ks[2 * rp][tc];
      u16x8 v1 = *(const u16x8*)&Ks[2 * rp + 1][tc];
#pragma unroll
      for (int j = 0; j < 8; j++) {
        *(unsigned int*)&Vt[dcc * 8 + j][2 * rp] =
            (unsigned int)v0[j] | ((unsigned int)v1[j] << 16);
      }
    }

    f32x4 s4[4] = {};
    __builtin_amdgcn_s_setprio(1);
#pragma unroll
    for (int jt = 0; jt < 4; jt++) {
      s16x8 b0 = *(const s16x8*)&Ks[16 * jt + l15][cb0];
      s16x8 b1 = *(const s16x8*)&Ks[16 * jt + l15][cb1];
      s4[jt] = MFMA_BF16(aq0, b0, s4[jt]);
      s4[jt] = MFMA_BF16(aq1, b1, s4[jt]);
      s4[jt] *= 0.125f;  // 1/sqrt(64)
    }
    __builtin_amdgcn_s_setprio(0);

#pragma unroll
    for (int r = 0; r < 4; r++) {
      float mx = mrow[r];
#pragma unroll
      for (int jt = 0; jt < 4; jt++) mx = fmaxf(mx, s4[jt][r]);
#pragma unroll
      for (int m = 1; m <= 8; m <<= 1) mx = fmaxf(mx, __shfl_xor(mx, m, 64));
      float al = __expf(mrow[r] - mx);
      mrow[r] = mx;
      float pv[4], sum = 0.f;
#pragma unroll
      for (int jt = 0; jt < 4; jt++) { pv[jt] = __expf(s4[jt][r] - mx); sum += pv[jt]; }
#pragma unroll
      for (int m = 1; m <= 8; m <<= 1) sum += __shfl_xor(sum, m, 64);
      lrow[r] = lrow[r] * al + sum;
#pragma unroll
      for (int jt = 0; jt < 4; jt++) o[jt][r] *= al;
#pragma unroll
      for (int jt = 0; jt < 4; jt++) Ps[16 * w + quad * 4 + r][16 * jt + l15] = f2b(pv[jt]);
    }
    __syncthreads();

    s16x8 ap0 = *(const s16x8*)&Ps[16 * w + l15][quad * 8];
    s16x8 ap1 = *(const s16x8*)&Ps[16 * w + l15][32 + quad * 8];
    __builtin_amdgcn_s_setprio(1);
#pragma unroll
    for (int jt = 0; jt < 4; jt++) {
      s16x8 bv0 = *(const s16x8*)&Vt[16 * jt + l15][quad * 8];
      s16x8 bv1 = *(const s16x8*)&Vt[16 * jt + l15][32 + quad * 8];
      o[jt] = MFMA_BF16(ap0, bv0, o[jt]);
      o[jt] = MFMA_BF16(ap1, bv1, o[jt]);
    }
    __builtin_amdgcn_s_setprio(0);
  }

  const int hk = h * KVS + kvs;
#pragma unroll
  for (int r = 0; r < 4; r++) {
    int q = q0 + 16 * w + quad * 4 + r;
    size_t base = (size_t)q * (KVS * NHEAD) + hk;
#pragma unroll
    for (int jt = 0; jt < 4; jt++)
      Opart[base * 64 + 16 * jt + l15] = f2b(o[jt][r]);
    if (l15 == 0) {
      Mpart[base] = mrow[r];
      Lpart[base] = lrow[r];
    }
  }
}

// ---------------------------------------------------------------- fused post-attention
// Block per token, 4 waves (wave w owns heads 3w..3w+2), 2 barriers.
__global__ __launch_bounds__(256) void fused_post_kernel(
    const u16* __restrict__ Opart, const float* __restrict__ Mpart,
    const float* __restrict__ Lpart, const float* __restrict__ x,
    const float* __restrict__ n3w, const float* __restrict__ gw,
    u16* __restrict__ xfb, float* __restrict__ out,
    int* __restrict__ counts, int* __restrict__ toklist, float* __restrict__ wtlist) {
  const int t = blockIdx.x;
  const int tid = threadIdx.x;
  const int lane = tid & 63, w = tid >> 6;
  __shared__ u16 Os[48 * 64];     // 6KB staged Opart row
  __shared__ float MsLs[96];      // [0,48): M, [48,96): L
  __shared__ float ssP[4];
  __shared__ float geP[4][NEXP];

  const u16* orow = Opart + (size_t)t * (48 * 64);
  for (int c = tid; c < 384; c += 256)
    *(u16x8*)&Os[c * 8] = *(const u16x8*)&orow[c * 8];
  if (tid < 96)
    MsLs[tid] = (tid < 48) ? Mpart[(size_t)t * 48 + tid]
                           : Lpart[(size_t)t * 48 + (tid - 48)];
  __syncthreads();

  float val[3];
  float ss = 0.f;
  const float* xr = x + (size_t)t * DMODEL;
  float* outr = out + (size_t)t * DMODEL;
#pragma unroll
  for (int j = 0; j < 3; j++) {
    const int ii = 3 * w + j;
    float m0 = MsLs[ii * 4 + 0], m1 = MsLs[ii * 4 + 1];
    float m2 = MsLs[ii * 4 + 2], m3 = MsLs[ii * 4 + 3];
    float mh = fmaxf(fmaxf(m0, m1), fmaxf(m2, m3));
    float c0 = __expf(m0 - mh), c1 = __expf(m1 - mh);
    float c2 = __expf(m2 - mh), c3 = __expf(m3 - mh);
    float Lh = c0 * MsLs[48 + ii * 4 + 0] + c1 * MsLs[48 + ii * 4 + 1] +
               c2 * MsLs[48 + ii * 4 + 2] + c3 * MsLs[48 + ii * 4 + 3];
    float O = c0 * b2f(Os[(ii * 4 + 0) * 64 + lane]) +
              c1 * b2f(Os[(ii * 4 + 1) * 64 + lane]) +
              c2 * b2f(Os[(ii * 4 + 2) * 64 + lane]) +
              c3 * b2f(Os[(ii * 4 + 3) * 64 + lane]);
    float v = xr[ii * 64 + lane] + O / Lh;
    outr[ii * 64 + lane] = v;
    val[j] = v;
    ss += v * v;
  }
#pragma unroll
  for (int off = 32; off >= 1; off >>= 1) ss += __shfl_xor(ss, off, 64);
  if (lane == 0) ssP[w] = ss;
  __syncthreads();
  float rms = rsqrtf((ssP[0] + ssP[1] + ssP[2] + ssP[3]) * (1.f / DMODEL) + 1e-5f);

  float ge[NEXP] = {};
#pragma unroll
  for (int j = 0; j < 3; j++) {
    int c = (3 * w + j) * 64 + lane;
    float xn = val[j] * rms * n3w[c];
    xfb[(size_t)t * DMODEL + c] = f2b(xn);
#pragma unroll
    for (int e = 0; e < NEXP; e++) ge[e] = fmaf(xn, gw[e * DMODEL + c], ge[e]);
  }
#pragma unroll
  for (int off = 32; off >= 1; off >>= 1)
#pragma unroll
    for (int e = 0; e < NEXP; e++) ge[e] += __shfl_xor(ge[e], off, 64);
  if (lane == 0)
#pragma unroll
    for (int e = 0; e < NEXP; e++) geP[w][e] = ge[e];
  __syncthreads();

  if (tid == 0) {
    float p[NEXP], mx = -INFINITY, s = 0.f;
#pragma unroll
    for (int e = 0; e < NEXP; e++) {
      p[e] = geP[0][e] + geP[1][e] + geP[2][e] + geP[3][e];
      mx = fmaxf(mx, p[e]);
    }
#pragma unroll
    for (int e = 0; e < NEXP; e++) { p[e] = __expf(p[e] - mx); s += p[e]; }
    int e0 = 0; float b0 = p[0];
    for (int e = 1; e < NEXP; e++) if (p[e] > b0) { b0 = p[e]; e0 = e; }
    int e1 = -1; float b1v = -1.f;
    for (int e = 0; e < NEXP; e++) if (e != e0 && p[e] > b1v) { b1v = p[e]; e1 = e; }
    float inv = 1.f / s;
    int pos0 = atomicAdd(&counts[e0], 1);
    toklist[e0 * SEQ + pos0] = t;
    wtlist[e0 * SEQ + pos0] = fmaxf(b0 * inv, 1e-7f);
    int pos1 = atomicAdd(&counts[e1], 1);
    toklist[e1 * SEQ + pos1] = t;
    wtlist[e1 * SEQ + pos1] = fmaxf(b1v * inv, 1e-7f);
  }
}

// ---------------------------------------------------------------- GEMM1: fused SwiGLU, 10 experts
// 64x64 tile, BK=64 single-buffered (one vmcnt drain per 64 K-cols), 8-chunk XOR swizzle.
// grid.x = 16 n-tiles: blockid%8 = x%8 -> weight panel pinned to one XCD L2.
__global__ __launch_bounds__(256) void gemm1_kernel(
    const u16* __restrict__ xfb,
    const u16* __restrict__ w1b, const u16* __restrict__ w3b, const u16* __restrict__ fc1b,
    const float* __restrict__ b1, const float* __restrict__ b3, const float* __restrict__ fc1_b,
    const int* __restrict__ counts, const int* __restrict__ toklist, u16* __restrict__ hb) {
  __shared__ u16 As[64][64];
  __shared__ u16 W1s[64][64];
  __shared__ u16 W3s[64][64];
  __shared__ int rIdx[64];
  const int e = blockIdx.z;
  const bool routed = (e < NEXP);
  int cnt, off;
  if (routed) {
    cnt = counts[e];
    off = 0;
    for (int i = 0; i < e; i++) off += counts[i];
  } else {
    cnt = SEQ;
    off = 2 * SEQ + (e - NEXP) * SEQ;
  }
  const int m0 = blockIdx.y * 64;
  if (m0 >= cnt) return;
  const int n0 = blockIdx.x * 64;
  const int tid = threadIdx.x;
  if (tid < 64) {
    int rr = m0 + tid;
    rIdx[tid] = routed ? toklist[e * SEQ + (rr < cnt ? rr : cnt - 1)] : rr;
  }
  __syncthreads();
  const u16* W1 = routed ? w1b + (size_t)e * IDIM * DMODEL
                         : fc1b + (size_t)(e - NEXP) * IDIM * DMODEL;
  const ptrdiff_t d31 = w3b - w1b;   // W3 row = W1 row + d31 (routed only)

  const int lane = tid & 63, w = tid >> 6;
  const int quad = lane >> 4, l15 = lane & 15;
  const int wy = w >> 1, wx = w & 1;
  const int lr8 = lane >> 3;                       // row within 8-row staging slab
  const int sch = ((lane & 7) ^ lr8) * 8;          // pre-swizzled source chunk (u16)

  const u16 *aS[2], *w1S[2];
#pragma unroll
  for (int c = 0; c < 2; c++) {
    int tr = 16 * w + 8 * c + lr8;
    aS[c]  = xfb + (size_t)rIdx[tr] * DMODEL + sch;
    w1S[c] = W1 + (size_t)(n0 + tr) * DMODEL + sch;
  }

  f32x4 acc1[2][2] = {};
  f32x4 acc3[2][2] = {};
  for (int k0 = 0; k0 < DMODEL; k0 += 64) {
#pragma unroll
    for (int c = 0; c < 2; c++) glds16(aS[c] + k0, &As[16 * w + 8 * c][0]);
#pragma unroll
    for (int c = 0; c < 2; c++) glds16(w1S[c] + k0, &W1s[16 * w + 8 * c][0]);
    if (routed) {
#pragma unroll
      for (int c = 0; c < 2; c++) glds16(w1S[c] + d31 + k0, &W3s[16 * w + 8 * c][0]);
    }
    __syncthreads();
#pragma unroll
    for (int kk = 0; kk < 2; kk++) {
      const int cb = (((kk * 4 + quad) ^ (l15 & 7))) * 8;
      s16x8 af[2], w1f[2];
#pragma unroll
      for (int i = 0; i < 2; i++) af[i] = *(const s16x8*)&As[32 * wy + 16 * i + l15][cb];
#pragma unroll
      for (int j = 0; j < 2; j++) w1f[j] = *(const s16x8*)&W1s[32 * wx + 16 * j + l15][cb];
#pragma unroll
      for (int i = 0; i < 2; i++)
#pragma unroll
        for (int j = 0; j < 2; j++)
          acc1[i][j] = MFMA_BF16(af[i], w1f[j], acc1[i][j]);
      if (routed) {
        s16x8 w3f[2];
#pragma unroll
        for (int j = 0; j < 2; j++) w3f[j] = *(const s16x8*)&W3s[32 * wx + 16 * j + l15][cb];
#pragma unroll
        for (int i = 0; i < 2; i++)
#pragma unroll
          for (int j = 0; j < 2; j++)
            acc3[i][j] = MFMA_BF16(af[i], w3f[j], acc3[i][j]);
      }
    }
    __syncthreads();
  }

#pragma unroll
  for (int j = 0; j < 2; j++) {
    int n = n0 + 32 * wx + 16 * j + l15;
    float b1v = routed ? b1[e * IDIM + n] : fc1_b[(e - NEXP) * IDIM + n];
    float b3v = routed ? b3[e * IDIM + n] : 0.f;
#pragma unroll
    for (int i = 0; i < 2; i++) {
#pragma unroll
      for (int r = 0; r < 4; r++) {
        int rr = m0 + 32 * wy + 16 * i + quad * 4 + r;
        if (rr < cnt) {
          float a = acc1[i][j][r] + b1v;
          float g = routed ? (acc3[i][j][r] + b3v) : 1.f;
          float hv = a / (1.f + __expf(-a)) * g;
          hb[(size_t)(off + rr) * IDIM + n] = f2b(hv);
        }
      }
    }
  }
}

// ---------------------------------------------------------------- GEMM2: down-proj, 10 experts
// 64x128 tile, BK=64 single-buffered, 8-chunk XOR swizzle, no K-split.
// grid.x padded to 8 so panel (n,e) -> XCD n pinning holds; n-tiles 6,7 exit.
__global__ __launch_bounds__(256) void gemm2_kernel(
    const u16* __restrict__ hb,
    const u16* __restrict__ w2b, const u16* __restrict__ fc2b,
    const float* __restrict__ b2, const float* __restrict__ fc2_b,
    const int* __restrict__ counts, const int* __restrict__ toklist,
    const float* __restrict__ wtlist, float* __restrict__ out) {
  __shared__ u16 As[64][64];
  __shared__ u16 Ws[128][64];
  const int n0 = blockIdx.x * 128;
  if (n0 >= DMODEL) return;
  const int e = blockIdx.z;
  const bool routed = (e < NEXP);
  int cnt, off;
  if (routed) {
    cnt = counts[e];
    off = 0;
    for (int i = 0; i < e; i++) off += counts[i];
  } else {
    cnt = SEQ;
    off = 2 * SEQ + (e - NEXP) * SEQ;
  }
  const int m0 = blockIdx.y * 64;
  if (m0 >= cnt) return;
  const int tid = threadIdx.x;

  const u16* Wb; int ldw, kof;
  if (routed) { Wb = w2b + (size_t)e * DMODEL * IDIM; ldw = IDIM; kof = 0; }
  else        { Wb = fc2b;                            ldw = ISH;  kof = (e - NEXP) * IDIM; }

  const int lane = tid & 63, w = tid >> 6;
  const int quad = lane >> 4, l15 = lane & 15;
  const int wy = w >> 1, wx = w & 1;
  const int lr8 = lane >> 3;
  const int sch = ((lane & 7) ^ lr8) * 8;

  const u16* aS[2];
#pragma unroll
  for (int c = 0; c < 2; c++) {
    int ra = m0 + 16 * w + 8 * c + lr8;
    ra = off + (ra < cnt ? ra : cnt - 1);
    aS[c] = hb + (size_t)ra * IDIM + sch;
  }
  const u16* wS[4];
#pragma unroll
  for (int c = 0; c < 4; c++) {
    int nr = n0 + 32 * w + 8 * c + lr8;
    wS[c] = Wb + (size_t)nr * ldw + kof + sch;
  }

  f32x4 acc[2][4] = {};
  for (int k0 = 0; k0 < IDIM; k0 += 64) {
#pragma unroll
    for (int c = 0; c < 2; c++) glds16(aS[c] + k0, &As[16 * w + 8 * c][0]);
#pragma unroll
    for (int c = 0; c < 4; c++) glds16(wS[c] + k0, &Ws[32 * w + 8 * c][0]);
    __syncthreads();
#pragma unroll
    for (int kk = 0; kk < 2; kk++) {
      const int cb = (((kk * 4 + quad) ^ (l15 & 7))) * 8;
      s16x8 af[2], wf[4];
#pragma unroll
      for (int i = 0; i < 2; i++) af[i] = *(const s16x8*)&As[32 * wy + 16 * i + l15][cb];
#pragma unroll
      for (int j = 0; j < 4; j++) wf[j] = *(const s16x8*)&Ws[64 * wx + 16 * j + l15][cb];
#pragma unroll
      for (int i = 0; i < 2; i++)
#pragma unroll
        for (int j = 0; j < 4; j++)
          acc[i][j] = MFMA_BF16(af[i], wf[j], acc[i][j]);
    }
    __syncthreads();
  }

#pragma unroll
  for (int j = 0; j < 4; j++) {
    int n = n0 + 64 * wx + 16 * j + l15;
    float bv = routed ? b2[e * DMODEL + n] : (e == NEXP ? fc2_b[n] : 0.f);
#pragma unroll
    for (int i = 0; i < 2; i++) {
#pragma unroll
      for (int r = 0; r < 4; r++) {
        int rr = m0 + 32 * wy + 16 * i + quad * 4 + r;
        if (rr < cnt) {
          int tok; float wt;
          if (routed) { tok = toklist[e * SEQ + rr]; wt = wtlist[e * SEQ + rr]; }
          else        { tok = rr;                    wt = 1.f; }
          atomicAdd(&out[(size_t)tok * DMODEL + n], wt * (acc[i][j][r] + bv));
        }
      }
    }
  }
}

// ---------------------------------------------------------------- launch
extern "C" void kernel_launch(void* const* d_in, const int* in_sizes, int n_in,
                              void* d_out, int out_size, void* d_ws, size_t ws_size,
                              hipStream_t stream) {
  const float* x       = (const float*)d_in[0];
  const float* norm1_w = (const float*)d_in[1];
  const float* norm3_w = (const float*)d_in[2];
  const float* gate_w  = (const float*)d_in[3];
  const float* w1      = (const float*)d_in[4];
  const float* b1      = (const float*)d_in[5];
  const float* w2      = (const float*)d_in[6];
  const float* b2      = (const float*)d_in[7];
  const float* w3      = (const float*)d_in[8];
  const float* b3      = (const float*)d_in[9];
  const float* fc1_w   = (const float*)d_in[10];
  const float* fc1_b   = (const float*)d_in[11];
  const float* fc2_w   = (const float*)d_in[12];
  const float* fc2_b   = (const float*)d_in[13];
  float* out = (float*)d_out;

  // workspace layout
  char* p = (char*)d_ws;
  u16*   xnb    = (u16*)p;   p += (size_t)SEQ * DMODEL * 2;
  u16*   xfb    = (u16*)p;   p += (size_t)SEQ * DMODEL * 2;
  u16*   hb     = (u16*)p;   p += (size_t)4 * SEQ * IDIM * 2;        // 8192 slots
  u16*   Opart  = (u16*)p;   p += (size_t)KVS * NHEAD * SEQ * 64 * 2;
  float* Mpart  = (float*)p; p += (size_t)KVS * NHEAD * SEQ * 4;
  float* Lpart  = (float*)p; p += (size_t)KVS * NHEAD * SEQ * 4;
  u16*   w1b    = (u16*)p;   p += (size_t)NEXP * IDIM * DMODEL * 2;
  u16*   w3b    = (u16*)p;   p += (size_t)NEXP * IDIM * DMODEL * 2;
  u16*   w2b    = (u16*)p;   p += (size_t)NEXP * DMODEL * IDIM * 2;
  u16*   fc1b   = (u16*)p;   p += (size_t)ISH * DMODEL * 2;
  u16*   fc2b   = (u16*)p;   p += (size_t)DMODEL * ISH * 2;
  int*   counts = (int*)p;   p += 256;
  int*   toklist= (int*)p;   p += (size_t)NEXP * SEQ * 4;
  float* wtlist = (float*)p; p += (size_t)NEXP * SEQ * 4;

  rmsnorm_kernel<<<SEQ, 256, 0, stream>>>(x, norm1_w, xnb, counts);
  attn_cvt_kernel<<<ATTN_BLOCKS + CVT_BLOCKS, 256, 0, stream>>>(
      xnb, Opart, Mpart, Lpart, w1, w3, w2, fc1_w, fc2_w,
      w1b, w3b, w2b, fc1b, fc2b);
  fused_post_kernel<<<SEQ, 256, 0, stream>>>(Opart, Mpart, Lpart, x, norm3_w, gate_w,
                                             xfb, out, counts, toklist, wtlist);
  gemm1_kernel<<<dim3(IDIM / 64, SEQ / 64, NE2), 256, 0, stream>>>(
      xfb, w1b, w3b, fc1b, b1, b3, fc1_b, counts, toklist, hb);
  gemm2_kernel<<<dim3(8, SEQ / 64, NE2), 256, 0, stream>>>(
      hb, w2b, fc2b, b2, fc2_b, counts, toklist, wtlist, out);
  (void)in_sizes; (void)n_in; (void)out_size; (void)ws_size;
}

// Round 10
// 313.755 us; speedup vs baseline: 1.0375x; 1.0375x over previous
//
#include <hip/hip_runtime.h>
#include <math.h>

#define SEQ    2048
#define DMODEL 768
#define NHEAD  12
#define NEXP   8
#define IDIM   1024
#define ISH    2048
#define KVS    4
#define NE2    10   // 8 routed experts + 2 shared-expert halves
#define ATTN_BLOCKS 1536  // 32 q-tiles * 12 heads * 4 kv-splits
#define CVT_BLOCKS 10752  // (3*786432 + 2*196608)/256 exactly

typedef unsigned short u16;
typedef short s16x8 __attribute__((ext_vector_type(8)));
typedef u16   u16x8 __attribute__((ext_vector_type(8)));
typedef float f32x4 __attribute__((ext_vector_type(4)));

#define MFMA_BF16(a, b, c) __builtin_amdgcn_mfma_f32_16x16x32_bf16((a), (b), (c), 0, 0, 0)

__device__ __forceinline__ void glds16(const void* g, void* l) {
  __builtin_amdgcn_global_load_lds(
      (const __attribute__((address_space(1))) unsigned int*)g,
      (__attribute__((address_space(3))) unsigned int*)l, 16, 0, 0);
}

__device__ __forceinline__ u16 f2b(float f) {  // fp32 -> bf16 RNE
  unsigned int u = __float_as_uint(f);
  unsigned int r = u + 0x7fffu + ((u >> 16) & 1u);
  return (u16)(r >> 16);
}
__device__ __forceinline__ float b2f(u16 v) {
  return __uint_as_float(((unsigned int)v) << 16);
}

// ---------------------------------------------------------------- rmsnorm1 (+ zero counts)
// Wave per row (4 rows/block), shuffle-only reductions, no barriers.
__global__ __launch_bounds__(256) void rmsnorm_kernel(const float* __restrict__ x,
                                                      const float* __restrict__ n1w,
                                                      u16* __restrict__ xnb,
                                                      int* __restrict__ counts) {
  const int tid = threadIdx.x;
  if (blockIdx.x == 0 && tid < 16) counts[tid] = 0;
  const int lane = tid & 63, w = tid >> 6;
  const int row = blockIdx.x * 4 + w;
  const float* r = x + (size_t)row * DMODEL;
  float v[12];
  float ss = 0.f;
#pragma unroll
  for (int i = 0; i < 12; i++) { v[i] = r[i * 64 + lane]; ss += v[i] * v[i]; }
#pragma unroll
  for (int off = 32; off >= 1; off >>= 1) ss += __shfl_xor(ss, off, 64);
  float rms = rsqrtf(ss * (1.f / DMODEL) + 1e-5f);
  u16* ob = xnb + (size_t)row * DMODEL;
#pragma unroll
  for (int i = 0; i < 12; i++) ob[i * 64 + lane] = f2b(v[i] * rms * n1w[i * 64 + lane]);
}

// ---------------------------------------------------------------- merged: MFMA flash attention
// (blocks [0,ATTN_BLOCKS)) + weight conversion (blocks after).
// All 4 LDS tiles are [64][64] chunk-XOR-swizzled (key=(row>>1)&7) -> 32KB, 5 blocks/CU.
__global__ __launch_bounds__(256) void attn_cvt_kernel(
    const u16* __restrict__ xnb, u16* __restrict__ Opart,
    float* __restrict__ Mpart, float* __restrict__ Lpart,
    const float* __restrict__ w1, const float* __restrict__ w3, const float* __restrict__ w2,
    const float* __restrict__ fc1, const float* __restrict__ fc2,
    u16* __restrict__ w1b, u16* __restrict__ w3b, u16* __restrict__ w2b,
    u16* __restrict__ fc1b, u16* __restrict__ fc2b) {
  const int tid = threadIdx.x;
  if (blockIdx.x >= ATTN_BLOCKS) {
    // ---- weight cvt ----
    long i = (long)(blockIdx.x - ATTN_BLOCKS) * 256 + tid;
    const long NW8 = (long)NEXP * IDIM * DMODEL / 8;   // 786432
    const long NF8 = (long)ISH * DMODEL / 8;           // 196608
    const float* s; u16* d; long o;
    if      (i < NW8)             { s = w1;  d = w1b;  o = i; }
    else if (i < 2 * NW8)         { s = w3;  d = w3b;  o = i - NW8; }
    else if (i < 3 * NW8)         { s = w2;  d = w2b;  o = i - 2 * NW8; }
    else if (i < 3 * NW8 + NF8)   { s = fc1; d = fc1b; o = i - 3 * NW8; }
    else                          { s = fc2; d = fc2b; o = i - 3 * NW8 - NF8; }
    float4 a = ((const float4*)s)[2 * o], b = ((const float4*)s)[2 * o + 1];
    u16x8 v;
    v[0] = f2b(a.x); v[1] = f2b(a.y); v[2] = f2b(a.z); v[3] = f2b(a.w);
    v[4] = f2b(b.x); v[5] = f2b(b.y); v[6] = f2b(b.z); v[7] = f2b(b.w);
    ((u16x8*)d)[o] = v;
    return;
  }
  // ---- attention ----
  __shared__ u16 Qs[64][64];   // slot (r, c) holds global chunk c ^ ((r>>1)&7)
  __shared__ u16 Ks[64][64];
  __shared__ u16 Vt[64][64];   // transposed V: [d][k], same swizzle
  __shared__ u16 Ps[64][64];   // P in A-layout: [q][k], same swizzle
  const int q0 = (blockIdx.x & 31) * 64;
  const int h = (blockIdx.x >> 5) % NHEAD;
  const int kvs = blockIdx.x / (32 * NHEAD);
  const int lane = tid & 63, w = tid >> 6;
  const int quad = lane >> 4, l15 = lane & 15;
  const size_t hoff = (size_t)h * 64;

  const int lr8 = lane >> 3, b7 = lane & 7;
  // staging source chunks (pre-swizzled): c=0 key = (lr8>>1), c=1 key = 4+(lr8>>1)
  const int sch0 = (b7 ^ (lr8 >> 1)) * 8;
  const int sch1 = (b7 ^ (4 + (lr8 >> 1))) * 8;
  const int rkey = (l15 >> 1) & 7;           // fragment read key for row (16*jt + l15)
  const int cb0 = (quad ^ rkey) * 8;         // global chunk quad
  const int cb1 = ((4 + quad) ^ rkey) * 8;   // global chunk 4+quad

  glds16(xnb + (size_t)(q0 + 16 * w + lr8) * DMODEL + hoff + sch0, &Qs[16 * w][0]);
  glds16(xnb + (size_t)(q0 + 16 * w + 8 + lr8) * DMODEL + hoff + sch1, &Qs[16 * w + 8][0]);
  __syncthreads();
  const s16x8 aq0 = *(const s16x8*)&Qs[16 * w + l15][cb0];
  const s16x8 aq1 = *(const s16x8*)&Qs[16 * w + l15][cb1];

  f32x4 o[4] = {};
  float mrow[4], lrow[4];
#pragma unroll
  for (int r = 0; r < 4; r++) { mrow[r] = -INFINITY; lrow[r] = 0.f; }

  const int it0 = kvs * (SEQ / 64 / KVS);
  for (int it = 0; it < SEQ / 64 / KVS; it++) {
    const int k0 = (it0 + it) * 64;
    glds16(xnb + (size_t)(k0 + 16 * w + lr8) * DMODEL + hoff + sch0, &Ks[16 * w][0]);
    glds16(xnb + (size_t)(k0 + 16 * w + 8 + lr8) * DMODEL + hoff + sch1, &Ks[16 * w + 8][0]);
    __syncthreads();

    {
      // transpose K -> Vt; Ks rows 2rp,2rp+1 share key rp&7
      const int rp = tid & 31, dcc = (tid >> 5) & 7;
      const int tc = (dcc ^ (rp & 7)) * 8;
      u16x8 v0 = *(const u16x8*)&Ks[2 * rp][tc];
      u16x8 v1 = *(const u16x8*)&Ks[2 * rp + 1][tc];
#pragma unroll
      for (int j = 0; j < 8; j++) {
        const int vrow = dcc * 8 + j;
        const int vkey = (vrow >> 1) & 7;
        *(unsigned int*)&Vt[vrow][((rp >> 2) ^ vkey) * 8 + (rp & 3) * 2] =
            (unsigned int)v0[j] | ((unsigned int)v1[j] << 16);
      }
    }

    f32x4 s4[4] = {};
    __builtin_amdgcn_s_setprio(1);
#pragma unroll
    for (int jt = 0; jt < 4; jt++) {
      s16x8 b0 = *(const s16x8*)&Ks[16 * jt + l15][cb0];
      s16x8 b1 = *(const s16x8*)&Ks[16 * jt + l15][cb1];
      s4[jt] = MFMA_BF16(aq0, b0, s4[jt]);
      s4[jt] = MFMA_BF16(aq1, b1, s4[jt]);
      s4[jt] *= 0.125f;  // 1/sqrt(64)
    }
    __builtin_amdgcn_s_setprio(0);

#pragma unroll
    for (int r = 0; r < 4; r++) {
      float mx = mrow[r];
#pragma unroll
      for (int jt = 0; jt < 4; jt++) mx = fmaxf(mx, s4[jt][r]);
#pragma unroll
      for (int m = 1; m <= 8; m <<= 1) mx = fmaxf(mx, __shfl_xor(mx, m, 64));
      float al = __expf(mrow[r] - mx);
      mrow[r] = mx;
      float pv[4], sum = 0.f;
#pragma unroll
      for (int jt = 0; jt < 4; jt++) { pv[jt] = __expf(s4[jt][r] - mx); sum += pv[jt]; }
#pragma unroll
      for (int m = 1; m <= 8; m <<= 1) sum += __shfl_xor(sum, m, 64);
      lrow[r] = lrow[r] * al + sum;
#pragma unroll
      for (int jt = 0; jt < 4; jt++) o[jt][r] *= al;
      const int pkey = ((quad * 4 + r) >> 1) & 7;   // key of row 16w+quad*4+r
#pragma unroll
      for (int jt = 0; jt < 4; jt++)
        Ps[16 * w + quad * 4 + r][((2 * jt + (l15 >> 3)) ^ pkey) * 8 + (l15 & 7)] =
            f2b(pv[jt]);
    }
    __syncthreads();

    s16x8 ap0 = *(const s16x8*)&Ps[16 * w + l15][cb0];
    s16x8 ap1 = *(const s16x8*)&Ps[16 * w + l15][cb1];
    __builtin_amdgcn_s_setprio(1);
#pragma unroll
    for (int jt = 0; jt < 4; jt++) {
      s16x8 bv0 = *(const s16x8*)&Vt[16 * jt + l15][cb0];
      s16x8 bv1 = *(const s16x8*)&Vt[16 * jt + l15][cb1];
      o[jt] = MFMA_BF16(ap0, bv0, o[jt]);
      o[jt] = MFMA_BF16(ap1, bv1, o[jt]);
    }
    __builtin_amdgcn_s_setprio(0);
  }

  const int hk = h * KVS + kvs;
#pragma unroll
  for (int r = 0; r < 4; r++) {
    int q = q0 + 16 * w + quad * 4 + r;
    size_t base = (size_t)q * (KVS * NHEAD) + hk;
#pragma unroll
    for (int jt = 0; jt < 4; jt++)
      Opart[base * 64 + 16 * jt + l15] = f2b(o[jt][r]);
    if (l15 == 0) {
      Mpart[base] = mrow[r];
      Lpart[base] = lrow[r];
    }
  }
}

// ---------------------------------------------------------------- fused post-attention
// Block per token, 4 waves (wave w owns heads 3w..3w+2), 2 barriers.
__global__ __launch_bounds__(256) void fused_post_kernel(
    const u16* __restrict__ Opart, const float* __restrict__ Mpart,
    const float* __restrict__ Lpart, const float* __restrict__ x,
    const float* __restrict__ n3w, const float* __restrict__ gw,
    u16* __restrict__ xfb, float* __restrict__ out,
    int* __restrict__ counts, int* __restrict__ toklist, float* __restrict__ wtlist) {
  const int t = blockIdx.x;
  const int tid = threadIdx.x;
  const int lane = tid & 63, w = tid >> 6;
  __shared__ u16 Os[48 * 64];     // 6KB staged Opart row
  __shared__ float MsLs[96];      // [0,48): M, [48,96): L
  __shared__ float ssP[4];
  __shared__ float geP[4][NEXP];

  const u16* orow = Opart + (size_t)t * (48 * 64);
  for (int c = tid; c < 384; c += 256)
    *(u16x8*)&Os[c * 8] = *(const u16x8*)&orow[c * 8];
  if (tid < 96)
    MsLs[tid] = (tid < 48) ? Mpart[(size_t)t * 48 + tid]
                           : Lpart[(size_t)t * 48 + (tid - 48)];
  __syncthreads();

  float val[3];
  float ss = 0.f;
  const float* xr = x + (size_t)t * DMODEL;
  float* outr = out + (size_t)t * DMODEL;
#pragma unroll
  for (int j = 0; j < 3; j++) {
    const int ii = 3 * w + j;
    float m0 = MsLs[ii * 4 + 0], m1 = MsLs[ii * 4 + 1];
    float m2 = MsLs[ii * 4 + 2], m3 = MsLs[ii * 4 + 3];
    float mh = fmaxf(fmaxf(m0, m1), fmaxf(m2, m3));
    float c0 = __expf(m0 - mh), c1 = __expf(m1 - mh);
    float c2 = __expf(m2 - mh), c3 = __expf(m3 - mh);
    float Lh = c0 * MsLs[48 + ii * 4 + 0] + c1 * MsLs[48 + ii * 4 + 1] +
               c2 * MsLs[48 + ii * 4 + 2] + c3 * MsLs[48 + ii * 4 + 3];
    float O = c0 * b2f(Os[(ii * 4 + 0) * 64 + lane]) +
              c1 * b2f(Os[(ii * 4 + 1) * 64 + lane]) +
              c2 * b2f(Os[(ii * 4 + 2) * 64 + lane]) +
              c3 * b2f(Os[(ii * 4 + 3) * 64 + lane]);
    float v = xr[ii * 64 + lane] + O / Lh;
    outr[ii * 64 + lane] = v;
    val[j] = v;
    ss += v * v;
  }
#pragma unroll
  for (int off = 32; off >= 1; off >>= 1) ss += __shfl_xor(ss, off, 64);
  if (lane == 0) ssP[w] = ss;
  __syncthreads();
  float rms = rsqrtf((ssP[0] + ssP[1] + ssP[2] + ssP[3]) * (1.f / DMODEL) + 1e-5f);

  float ge[NEXP] = {};
#pragma unroll
  for (int j = 0; j < 3; j++) {
    int c = (3 * w + j) * 64 + lane;
    float xn = val[j] * rms * n3w[c];
    xfb[(size_t)t * DMODEL + c] = f2b(xn);
#pragma unroll
    for (int e = 0; e < NEXP; e++) ge[e] = fmaf(xn, gw[e * DMODEL + c], ge[e]);
  }
#pragma unroll
  for (int off = 32; off >= 1; off >>= 1)
#pragma unroll
    for (int e = 0; e < NEXP; e++) ge[e] += __shfl_xor(ge[e], off, 64);
  if (lane == 0)
#pragma unroll
    for (int e = 0; e < NEXP; e++) geP[w][e] = ge[e];
  __syncthreads();

  if (tid == 0) {
    float p[NEXP], mx = -INFINITY, s = 0.f;
#pragma unroll
    for (int e = 0; e < NEXP; e++) {
      p[e] = geP[0][e] + geP[1][e] + geP[2][e] + geP[3][e];
      mx = fmaxf(mx, p[e]);
    }
#pragma unroll
    for (int e = 0; e < NEXP; e++) { p[e] = __expf(p[e] - mx); s += p[e]; }
    int e0 = 0; float b0 = p[0];
    for (int e = 1; e < NEXP; e++) if (p[e] > b0) { b0 = p[e]; e0 = e; }
    int e1 = -1; float b1v = -1.f;
    for (int e = 0; e < NEXP; e++) if (e != e0 && p[e] > b1v) { b1v = p[e]; e1 = e; }
    float inv = 1.f / s;
    int pos0 = atomicAdd(&counts[e0], 1);
    toklist[e0 * SEQ + pos0] = t;
    wtlist[e0 * SEQ + pos0] = fmaxf(b0 * inv, 1e-7f);
    int pos1 = atomicAdd(&counts[e1], 1);
    toklist[e1 * SEQ + pos1] = t;
    wtlist[e1 * SEQ + pos1] = fmaxf(b1v * inv, 1e-7f);
  }
}

// ---------------------------------------------------------------- GEMM1: fused SwiGLU, 10 experts
// 64x64 tile, BK=64 single-buffered, 8-chunk XOR swizzle. grid.x=16: panel pinned to one XCD.
__global__ __launch_bounds__(256) void gemm1_kernel(
    const u16* __restrict__ xfb,
    const u16* __restrict__ w1b, const u16* __restrict__ w3b, const u16* __restrict__ fc1b,
    const float* __restrict__ b1, const float* __restrict__ b3, const float* __restrict__ fc1_b,
    const int* __restrict__ counts, const int* __restrict__ toklist, u16* __restrict__ hb) {
  __shared__ u16 As[64][64];
  __shared__ u16 W1s[64][64];
  __shared__ u16 W3s[64][64];
  __shared__ int rIdx[64];
  const int e = blockIdx.z;
  const bool routed = (e < NEXP);
  int cnt, off;
  if (routed) {
    cnt = counts[e];
    off = 0;
    for (int i = 0; i < e; i++) off += counts[i];
  } else {
    cnt = SEQ;
    off = 2 * SEQ + (e - NEXP) * SEQ;
  }
  const int m0 = blockIdx.y * 64;
  if (m0 >= cnt) return;
  const int n0 = blockIdx.x * 64;
  const int tid = threadIdx.x;
  if (tid < 64) {
    int rr = m0 + tid;
    rIdx[tid] = routed ? toklist[e * SEQ + (rr < cnt ? rr : cnt - 1)] : rr;
  }
  __syncthreads();
  const u16* W1 = routed ? w1b + (size_t)e * IDIM * DMODEL
                         : fc1b + (size_t)(e - NEXP) * IDIM * DMODEL;
  const ptrdiff_t d31 = w3b - w1b;   // W3 row = W1 row + d31 (routed only)

  const int lane = tid & 63, w = tid >> 6;
  const int quad = lane >> 4, l15 = lane & 15;
  const int wy = w >> 1, wx = w & 1;
  const int lr8 = lane >> 3;                       // row within 8-row staging slab
  const int sch = ((lane & 7) ^ lr8) * 8;          // pre-swizzled source chunk (u16)

  const u16 *aS[2], *w1S[2];
#pragma unroll
  for (int c = 0; c < 2; c++) {
    int tr = 16 * w + 8 * c + lr8;
    aS[c]  = xfb + (size_t)rIdx[tr] * DMODEL + sch;
    w1S[c] = W1 + (size_t)(n0 + tr) * DMODEL + sch;
  }

  f32x4 acc1[2][2] = {};
  f32x4 acc3[2][2] = {};
  for (int k0 = 0; k0 < DMODEL; k0 += 64) {
#pragma unroll
    for (int c = 0; c < 2; c++) glds16(aS[c] + k0, &As[16 * w + 8 * c][0]);
#pragma unroll
    for (int c = 0; c < 2; c++) glds16(w1S[c] + k0, &W1s[16 * w + 8 * c][0]);
    if (routed) {
#pragma unroll
      for (int c = 0; c < 2; c++) glds16(w1S[c] + d31 + k0, &W3s[16 * w + 8 * c][0]);
    }
    __syncthreads();
#pragma unroll
    for (int kk = 0; kk < 2; kk++) {
      const int cb = (((kk * 4 + quad) ^ (l15 & 7))) * 8;
      s16x8 af[2], w1f[2];
#pragma unroll
      for (int i = 0; i < 2; i++) af[i] = *(const s16x8*)&As[32 * wy + 16 * i + l15][cb];
#pragma unroll
      for (int j = 0; j < 2; j++) w1f[j] = *(const s16x8*)&W1s[32 * wx + 16 * j + l15][cb];
#pragma unroll
      for (int i = 0; i < 2; i++)
#pragma unroll
        for (int j = 0; j < 2; j++)
          acc1[i][j] = MFMA_BF16(af[i], w1f[j], acc1[i][j]);
      if (routed) {
        s16x8 w3f[2];
#pragma unroll
        for (int j = 0; j < 2; j++) w3f[j] = *(const s16x8*)&W3s[32 * wx + 16 * j + l15][cb];
#pragma unroll
        for (int i = 0; i < 2; i++)
#pragma unroll
          for (int j = 0; j < 2; j++)
            acc3[i][j] = MFMA_BF16(af[i], w3f[j], acc3[i][j]);
      }
    }
    __syncthreads();
  }

#pragma unroll
  for (int j = 0; j < 2; j++) {
    int n = n0 + 32 * wx + 16 * j + l15;
    float b1v = routed ? b1[e * IDIM + n] : fc1_b[(e - NEXP) * IDIM + n];
    float b3v = routed ? b3[e * IDIM + n] : 0.f;
#pragma unroll
    for (int i = 0; i < 2; i++) {
#pragma unroll
      for (int r = 0; r < 4; r++) {
        int rr = m0 + 32 * wy + 16 * i + quad * 4 + r;
        if (rr < cnt) {
          float a = acc1[i][j][r] + b1v;
          float g = routed ? (acc3[i][j][r] + b3v) : 1.f;
          float hv = a / (1.f + __expf(-a)) * g;
          hb[(size_t)(off + rr) * IDIM + n] = f2b(hv);
        }
      }
    }
  }
}

// ---------------------------------------------------------------- GEMM2: down-proj, 10 experts
// 64x64 tile, BK=64 single-buffered, 8-chunk XOR swizzle (16KB -> 6 blocks/CU).
// grid.x padded to 16 so blockid%8 = x%8 -> W2 panel pinned to one XCD; x>=12 exit.
__global__ __launch_bounds__(256) void gemm2_kernel(
    const u16* __restrict__ hb,
    const u16* __restrict__ w2b, const u16* __restrict__ fc2b,
    const float* __restrict__ b2, const float* __restrict__ fc2_b,
    const int* __restrict__ counts, const int* __restrict__ toklist,
    const float* __restrict__ wtlist, float* __restrict__ out) {
  __shared__ u16 As[64][64];
  __shared__ u16 Ws[64][64];
  const int n0 = blockIdx.x * 64;
  if (n0 >= DMODEL) return;
  const int e = blockIdx.z;
  const bool routed = (e < NEXP);
  int cnt, off;
  if (routed) {
    cnt = counts[e];
    off = 0;
    for (int i = 0; i < e; i++) off += counts[i];
  } else {
    cnt = SEQ;
    off = 2 * SEQ + (e - NEXP) * SEQ;
  }
  const int m0 = blockIdx.y * 64;
  if (m0 >= cnt) return;
  const int tid = threadIdx.x;

  const u16* Wb; int ldw, kof;
  if (routed) { Wb = w2b + (size_t)e * DMODEL * IDIM; ldw = IDIM; kof = 0; }
  else        { Wb = fc2b;                            ldw = ISH;  kof = (e - NEXP) * IDIM; }

  const int lane = tid & 63, w = tid >> 6;
  const int quad = lane >> 4, l15 = lane & 15;
  const int wy = w >> 1, wx = w & 1;
  const int lr8 = lane >> 3;
  const int sch = ((lane & 7) ^ lr8) * 8;

  const u16 *aS[2], *wS[2];
#pragma unroll
  for (int c = 0; c < 2; c++) {
    int tr = 16 * w + 8 * c + lr8;
    int ra = m0 + tr;
    ra = off + (ra < cnt ? ra : cnt - 1);
    aS[c] = hb + (size_t)ra * IDIM + sch;
    wS[c] = Wb + (size_t)(n0 + tr) * ldw + kof + sch;
  }

  f32x4 acc[2][2] = {};
  for (int k0 = 0; k0 < IDIM; k0 += 64) {
#pragma unroll
    for (int c = 0; c < 2; c++) glds16(aS[c] + k0, &As[16 * w + 8 * c][0]);
#pragma unroll
    for (int c = 0; c < 2; c++) glds16(wS[c] + k0, &Ws[16 * w + 8 * c][0]);
    __syncthreads();
#pragma unroll
    for (int kk = 0; kk < 2; kk++) {
      const int cb = (((kk * 4 + quad) ^ (l15 & 7))) * 8;
      s16x8 af[2], wf[2];
#pragma unroll
      for (int i = 0; i < 2; i++) af[i] = *(const s16x8*)&As[32 * wy + 16 * i + l15][cb];
#pragma unroll
      for (int j = 0; j < 2; j++) wf[j] = *(const s16x8*)&Ws[32 * wx + 16 * j + l15][cb];
#pragma unroll
      for (int i = 0; i < 2; i++)
#pragma unroll
        for (int j = 0; j < 2; j++)
          acc[i][j] = MFMA_BF16(af[i], wf[j], acc[i][j]);
    }
    __syncthreads();
  }

#pragma unroll
  for (int j = 0; j < 2; j++) {
    int n = n0 + 32 * wx + 16 * j + l15;
    float bv = routed ? b2[e * DMODEL + n] : (e == NEXP ? fc2_b[n] : 0.f);
#pragma unroll
    for (int i = 0; i < 2; i++) {
#pragma unroll
      for (int r = 0; r < 4; r++) {
        int rr = m0 + 32 * wy + 16 * i + quad * 4 + r;
        if (rr < cnt) {
          int tok; float wt;
          if (routed) { tok = toklist[e * SEQ + rr]; wt = wtlist[e * SEQ + rr]; }
          else        { tok = rr;                    wt = 1.f; }
          atomicAdd(&out[(size_t)tok * DMODEL + n], wt * (acc[i][j][r] + bv));
        }
      }
    }
  }
}

// ---------------------------------------------------------------- launch
extern "C" void kernel_launch(void* const* d_in, const int* in_sizes, int n_in,
                              void* d_out, int out_size, void* d_ws, size_t ws_size,
                              hipStream_t stream) {
  const float* x       = (const float*)d_in[0];
  const float* norm1_w = (const float*)d_in[1];
  const float* norm3_w = (const float*)d_in[2];
  const float* gate_w  = (const float*)d_in[3];
  const float* w1      = (const float*)d_in[4];
  const float* b1      = (const float*)d_in[5];
  const float* w2      = (const float*)d_in[6];
  const float* b2      = (const float*)d_in[7];
  const float* w3      = (const float*)d_in[8];
  const float* b3      = (const float*)d_in[9];
  const float* fc1_w   = (const float*)d_in[10];
  const float* fc1_b   = (const float*)d_in[11];
  const float* fc2_w   = (const float*)d_in[12];
  const float* fc2_b   = (const float*)d_in[13];
  float* out = (float*)d_out;

  // workspace layout
  char* p = (char*)d_ws;
  u16*   xnb    = (u16*)p;   p += (size_t)SEQ * DMODEL * 2;
  u16*   xfb    = (u16*)p;   p += (size_t)SEQ * DMODEL * 2;
  u16*   hb     = (u16*)p;   p += (size_t)4 * SEQ * IDIM * 2;        // 8192 slots
  u16*   Opart  = (u16*)p;   p += (size_t)KVS * NHEAD * SEQ * 64 * 2;
  float* Mpart  = (float*)p; p += (size_t)KVS * NHEAD * SEQ * 4;
  float* Lpart  = (float*)p; p += (size_t)KVS * NHEAD * SEQ * 4;
  u16*   w1b    = (u16*)p;   p += (size_t)NEXP * IDIM * DMODEL * 2;
  u16*   w3b    = (u16*)p;   p += (size_t)NEXP * IDIM * DMODEL * 2;
  u16*   w2b    = (u16*)p;   p += (size_t)NEXP * DMODEL * IDIM * 2;
  u16*   fc1b   = (u16*)p;   p += (size_t)ISH * DMODEL * 2;
  u16*   fc2b   = (u16*)p;   p += (size_t)DMODEL * ISH * 2;
  int*   counts = (int*)p;   p += 256;
  int*   toklist= (int*)p;   p += (size_t)NEXP * SEQ * 4;
  float* wtlist = (float*)p; p += (size_t)NEXP * SEQ * 4;

  rmsnorm_kernel<<<SEQ / 4, 256, 0, stream>>>(x, norm1_w, xnb, counts);
  attn_cvt_kernel<<<ATTN_BLOCKS + CVT_BLOCKS, 256, 0, stream>>>(
      xnb, Opart, Mpart, Lpart, w1, w3, w2, fc1_w, fc2_w,
      w1b, w3b, w2b, fc1b, fc2b);
  fused_post_kernel<<<SEQ, 256, 0, stream>>>(Opart, Mpart, Lpart, x, norm3_w, gate_w,
                                             xfb, out, counts, toklist, wtlist);
  gemm1_kernel<<<dim3(IDIM / 64, SEQ / 64, NE2), 256, 0, stream>>>(
      xfb, w1b, w3b, fc1b, b1, b3, fc1_b, counts, toklist, hb);
  gemm2_kernel<<<dim3(16, SEQ / 64, NE2), 256, 0, stream>>>(
      hb, w2b, fc2b, b2, fc2_b, counts, toklist, wtlist, out);
  (void)in_sizes; (void)n_in; (void)out_size; (void)ws_size;
}

// Round 11
// 313.520 us; speedup vs baseline: 1.0383x; 1.0008x over previous
//
#include <hip/hip_runtime.h>
#include <math.h>

#define SEQ    2048
#define DMODEL 768
#define NHEAD  12
#define NEXP   8
#define IDIM   1024
#define ISH    2048
#define KVS    4
#define NE2    10   // 8 routed experts + 2 shared-expert halves
#define ATTN_BLOCKS 1536  // 32 q-tiles * 12 heads * 4 kv-splits
#define CVT_BLOCKS 10752  // (3*786432 + 2*196608)/256 exactly
#define QK_SCALE 0.18033688011112042f  // 0.125 * log2(e): softmax runs in exp2 domain

typedef unsigned short u16;
typedef short s16x8 __attribute__((ext_vector_type(8)));
typedef u16   u16x8 __attribute__((ext_vector_type(8)));
typedef float f32x4 __attribute__((ext_vector_type(4)));

#define MFMA_BF16(a, b, c) __builtin_amdgcn_mfma_f32_16x16x32_bf16((a), (b), (c), 0, 0, 0)

__device__ __forceinline__ void glds16(const void* g, void* l) {
  __builtin_amdgcn_global_load_lds(
      (const __attribute__((address_space(1))) unsigned int*)g,
      (__attribute__((address_space(3))) unsigned int*)l, 16, 0, 0);
}

__device__ __forceinline__ u16 f2b(float f) {  // fp32 -> bf16 RNE
  unsigned int u = __float_as_uint(f);
  unsigned int r = u + 0x7fffu + ((u >> 16) & 1u);
  return (u16)(r >> 16);
}
__device__ __forceinline__ float b2f(u16 v) {
  return __uint_as_float(((unsigned int)v) << 16);
}

// ---------------------------------------------------------------- rmsnorm1 (+ zero counts)
// Wave per row (4 rows/block), shuffle-only reductions, no barriers.
__global__ __launch_bounds__(256) void rmsnorm_kernel(const float* __restrict__ x,
                                                      const float* __restrict__ n1w,
                                                      u16* __restrict__ xnb,
                                                      int* __restrict__ counts) {
  const int tid = threadIdx.x;
  if (blockIdx.x == 0 && tid < 16) counts[tid] = 0;
  const int lane = tid & 63, w = tid >> 6;
  const int row = blockIdx.x * 4 + w;
  const float* r = x + (size_t)row * DMODEL;
  float v[12];
  float ss = 0.f;
#pragma unroll
  for (int i = 0; i < 12; i++) { v[i] = r[i * 64 + lane]; ss += v[i] * v[i]; }
#pragma unroll
  for (int off = 32; off >= 1; off >>= 1) ss += __shfl_xor(ss, off, 64);
  float rms = rsqrtf(ss * (1.f / DMODEL) + 1e-5f);
  u16* ob = xnb + (size_t)row * DMODEL;
#pragma unroll
  for (int i = 0; i < 12; i++) ob[i * 64 + lane] = f2b(v[i] * rms * n1w[i * 64 + lane]);
}

// ---------------------------------------------------------------- merged: MFMA flash attention
// (blocks [0,ATTN_BLOCKS)) + weight conversion (blocks after).
// LDS: QP (Qs early / Ps late - Qs is dead after fragment hoist), Ks, Vt = 24KB -> 6 blocks/CU.
// Softmax in exp2 domain (QK_SCALE folds log2 e); Mpart/Lpart are exp2-domain partials.
__global__ __launch_bounds__(256) void attn_cvt_kernel(
    const u16* __restrict__ xnb, u16* __restrict__ Opart,
    float* __restrict__ Mpart, float* __restrict__ Lpart,
    const float* __restrict__ w1, const float* __restrict__ w3, const float* __restrict__ w2,
    const float* __restrict__ fc1, const float* __restrict__ fc2,
    u16* __restrict__ w1b, u16* __restrict__ w3b, u16* __restrict__ w2b,
    u16* __restrict__ fc1b, u16* __restrict__ fc2b) {
  const int tid = threadIdx.x;
  if (blockIdx.x >= ATTN_BLOCKS) {
    // ---- weight cvt ----
    long i = (long)(blockIdx.x - ATTN_BLOCKS) * 256 + tid;
    const long NW8 = (long)NEXP * IDIM * DMODEL / 8;   // 786432
    const long NF8 = (long)ISH * DMODEL / 8;           // 196608
    const float* s; u16* d; long o;
    if      (i < NW8)             { s = w1;  d = w1b;  o = i; }
    else if (i < 2 * NW8)         { s = w3;  d = w3b;  o = i - NW8; }
    else if (i < 3 * NW8)         { s = w2;  d = w2b;  o = i - 2 * NW8; }
    else if (i < 3 * NW8 + NF8)   { s = fc1; d = fc1b; o = i - 3 * NW8; }
    else                          { s = fc2; d = fc2b; o = i - 3 * NW8 - NF8; }
    float4 a = ((const float4*)s)[2 * o], b = ((const float4*)s)[2 * o + 1];
    u16x8 v;
    v[0] = f2b(a.x); v[1] = f2b(a.y); v[2] = f2b(a.z); v[3] = f2b(a.w);
    v[4] = f2b(b.x); v[5] = f2b(b.y); v[6] = f2b(b.z); v[7] = f2b(b.w);
    ((u16x8*)d)[o] = v;
    return;
  }
  // ---- attention ----
  __shared__ u16 QP[64][64];   // Qs before the loop; Ps inside (aliased; Qs dead after hoist)
  __shared__ u16 Ks[64][64];   // slot (r, c) holds global chunk c ^ ((r>>1)&7)
  __shared__ u16 Vt[64][64];   // transposed V: [d][k], same swizzle
  const int q0 = (blockIdx.x & 31) * 64;
  const int h = (blockIdx.x >> 5) % NHEAD;
  const int kvs = blockIdx.x / (32 * NHEAD);
  const int lane = tid & 63, w = tid >> 6;
  const int quad = lane >> 4, l15 = lane & 15;
  const size_t hoff = (size_t)h * 64;

  const int lr8 = lane >> 3, b7 = lane & 7;
  // staging source chunks (pre-swizzled): c=0 key = (lr8>>1), c=1 key = 4+(lr8>>1)
  const int sch0 = (b7 ^ (lr8 >> 1)) * 8;
  const int sch1 = (b7 ^ (4 + (lr8 >> 1))) * 8;
  const int rkey = (l15 >> 1) & 7;           // fragment read key for row (16*jt + l15)
  const int cb0 = (quad ^ rkey) * 8;         // global chunk quad
  const int cb1 = ((4 + quad) ^ rkey) * 8;   // global chunk 4+quad

  glds16(xnb + (size_t)(q0 + 16 * w + lr8) * DMODEL + hoff + sch0, &QP[16 * w][0]);
  glds16(xnb + (size_t)(q0 + 16 * w + 8 + lr8) * DMODEL + hoff + sch1, &QP[16 * w + 8][0]);
  __syncthreads();
  const s16x8 aq0 = *(const s16x8*)&QP[16 * w + l15][cb0];
  const s16x8 aq1 = *(const s16x8*)&QP[16 * w + l15][cb1];

  f32x4 o[4] = {};
  float mrow[4], lrow[4];
#pragma unroll
  for (int r = 0; r < 4; r++) { mrow[r] = -INFINITY; lrow[r] = 0.f; }

  const int it0 = kvs * (SEQ / 64 / KVS);
  for (int it = 0; it < SEQ / 64 / KVS; it++) {
    const int k0 = (it0 + it) * 64;
    glds16(xnb + (size_t)(k0 + 16 * w + lr8) * DMODEL + hoff + sch0, &Ks[16 * w][0]);
    glds16(xnb + (size_t)(k0 + 16 * w + 8 + lr8) * DMODEL + hoff + sch1, &Ks[16 * w + 8][0]);
    __syncthreads();   // drains Q-frag ds_reads (iter 0) / PV reads (iter>0) before QP reuse

    {
      // transpose K -> Vt; Ks rows 2rp,2rp+1 share key rp&7
      const int rp = tid & 31, dcc = (tid >> 5) & 7;
      const int tc = (dcc ^ (rp & 7)) * 8;
      u16x8 v0 = *(const u16x8*)&Ks[2 * rp][tc];
      u16x8 v1 = *(const u16x8*)&Ks[2 * rp + 1][tc];
#pragma unroll
      for (int j = 0; j < 8; j++) {
        const int vrow = dcc * 8 + j;
        const int vkey = (vrow >> 1) & 7;
        *(unsigned int*)&Vt[vrow][((rp >> 2) ^ vkey) * 8 + (rp & 3) * 2] =
            (unsigned int)v0[j] | ((unsigned int)v1[j] << 16);
      }
    }

    f32x4 s4[4] = {};
    __builtin_amdgcn_s_setprio(1);
#pragma unroll
    for (int jt = 0; jt < 4; jt++) {
      s16x8 b0 = *(const s16x8*)&Ks[16 * jt + l15][cb0];
      s16x8 b1 = *(const s16x8*)&Ks[16 * jt + l15][cb1];
      s4[jt] = MFMA_BF16(aq0, b0, s4[jt]);
      s4[jt] = MFMA_BF16(aq1, b1, s4[jt]);
      s4[jt] *= QK_SCALE;   // exp2 domain
    }
    __builtin_amdgcn_s_setprio(0);

#pragma unroll
    for (int r = 0; r < 4; r++) {
      float mx = mrow[r];
#pragma unroll
      for (int jt = 0; jt < 4; jt++) mx = fmaxf(mx, s4[jt][r]);
#pragma unroll
      for (int m = 1; m <= 8; m <<= 1) mx = fmaxf(mx, __shfl_xor(mx, m, 64));
      float al = exp2f(mrow[r] - mx);
      mrow[r] = mx;
      float pv[4], sum = 0.f;
#pragma unroll
      for (int jt = 0; jt < 4; jt++) { pv[jt] = exp2f(s4[jt][r] - mx); sum += pv[jt]; }
#pragma unroll
      for (int m = 1; m <= 8; m <<= 1) sum += __shfl_xor(sum, m, 64);
      lrow[r] = lrow[r] * al + sum;
#pragma unroll
      for (int jt = 0; jt < 4; jt++) o[jt][r] *= al;
      const int pkey = ((quad * 4 + r) >> 1) & 7;   // key of row 16w+quad*4+r
#pragma unroll
      for (int jt = 0; jt < 4; jt++)
        QP[16 * w + quad * 4 + r][((2 * jt + (l15 >> 3)) ^ pkey) * 8 + (l15 & 7)] =
            f2b(pv[jt]);
    }
    __syncthreads();

    s16x8 ap0 = *(const s16x8*)&QP[16 * w + l15][cb0];
    s16x8 ap1 = *(const s16x8*)&QP[16 * w + l15][cb1];
    __builtin_amdgcn_s_setprio(1);
#pragma unroll
    for (int jt = 0; jt < 4; jt++) {
      s16x8 bv0 = *(const s16x8*)&Vt[16 * jt + l15][cb0];
      s16x8 bv1 = *(const s16x8*)&Vt[16 * jt + l15][cb1];
      o[jt] = MFMA_BF16(ap0, bv0, o[jt]);
      o[jt] = MFMA_BF16(ap1, bv1, o[jt]);
    }
    __builtin_amdgcn_s_setprio(0);
  }

  const int hk = h * KVS + kvs;
#pragma unroll
  for (int r = 0; r < 4; r++) {
    int q = q0 + 16 * w + quad * 4 + r;
    size_t base = (size_t)q * (KVS * NHEAD) + hk;
#pragma unroll
    for (int jt = 0; jt < 4; jt++)
      Opart[base * 64 + 16 * jt + l15] = f2b(o[jt][r]);
    if (l15 == 0) {
      Mpart[base] = mrow[r];
      Lpart[base] = lrow[r];
    }
  }
}

// ---------------------------------------------------------------- fused post-attention
// Block per token, 4 waves (wave w owns heads 3w..3w+2), 2 barriers.
// NOTE: M/L partials are exp2-domain -> combine with exp2f.
__global__ __launch_bounds__(256) void fused_post_kernel(
    const u16* __restrict__ Opart, const float* __restrict__ Mpart,
    const float* __restrict__ Lpart, const float* __restrict__ x,
    const float* __restrict__ n3w, const float* __restrict__ gw,
    u16* __restrict__ xfb, float* __restrict__ out,
    int* __restrict__ counts, int* __restrict__ toklist, float* __restrict__ wtlist) {
  const int t = blockIdx.x;
  const int tid = threadIdx.x;
  const int lane = tid & 63, w = tid >> 6;
  __shared__ u16 Os[48 * 64];     // 6KB staged Opart row
  __shared__ float MsLs[96];      // [0,48): M, [48,96): L
  __shared__ float ssP[4];
  __shared__ float geP[4][NEXP];

  const u16* orow = Opart + (size_t)t * (48 * 64);
  for (int c = tid; c < 384; c += 256)
    *(u16x8*)&Os[c * 8] = *(const u16x8*)&orow[c * 8];
  if (tid < 96)
    MsLs[tid] = (tid < 48) ? Mpart[(size_t)t * 48 + tid]
                           : Lpart[(size_t)t * 48 + (tid - 48)];
  __syncthreads();

  float val[3];
  float ss = 0.f;
  const float* xr = x + (size_t)t * DMODEL;
  float* outr = out + (size_t)t * DMODEL;
#pragma unroll
  for (int j = 0; j < 3; j++) {
    const int ii = 3 * w + j;
    float m0 = MsLs[ii * 4 + 0], m1 = MsLs[ii * 4 + 1];
    float m2 = MsLs[ii * 4 + 2], m3 = MsLs[ii * 4 + 3];
    float mh = fmaxf(fmaxf(m0, m1), fmaxf(m2, m3));
    float c0 = exp2f(m0 - mh), c1 = exp2f(m1 - mh);
    float c2 = exp2f(m2 - mh), c3 = exp2f(m3 - mh);
    float Lh = c0 * MsLs[48 + ii * 4 + 0] + c1 * MsLs[48 + ii * 4 + 1] +
               c2 * MsLs[48 + ii * 4 + 2] + c3 * MsLs[48 + ii * 4 + 3];
    float O = c0 * b2f(Os[(ii * 4 + 0) * 64 + lane]) +
              c1 * b2f(Os[(ii * 4 + 1) * 64 + lane]) +
              c2 * b2f(Os[(ii * 4 + 2) * 64 + lane]) +
              c3 * b2f(Os[(ii * 4 + 3) * 64 + lane]);
    float v = xr[ii * 64 + lane] + O / Lh;
    outr[ii * 64 + lane] = v;
    val[j] = v;
    ss += v * v;
  }
#pragma unroll
  for (int off = 32; off >= 1; off >>= 1) ss += __shfl_xor(ss, off, 64);
  if (lane == 0) ssP[w] = ss;
  __syncthreads();
  float rms = rsqrtf((ssP[0] + ssP[1] + ssP[2] + ssP[3]) * (1.f / DMODEL) + 1e-5f);

  float ge[NEXP] = {};
#pragma unroll
  for (int j = 0; j < 3; j++) {
    int c = (3 * w + j) * 64 + lane;
    float xn = val[j] * rms * n3w[c];
    xfb[(size_t)t * DMODEL + c] = f2b(xn);
#pragma unroll
    for (int e = 0; e < NEXP; e++) ge[e] = fmaf(xn, gw[e * DMODEL + c], ge[e]);
  }
#pragma unroll
  for (int off = 32; off >= 1; off >>= 1)
#pragma unroll
    for (int e = 0; e < NEXP; e++) ge[e] += __shfl_xor(ge[e], off, 64);
  if (lane == 0)
#pragma unroll
    for (int e = 0; e < NEXP; e++) geP[w][e] = ge[e];
  __syncthreads();

  if (tid == 0) {
    float p[NEXP], mx = -INFINITY, s = 0.f;
#pragma unroll
    for (int e = 0; e < NEXP; e++) {
      p[e] = geP[0][e] + geP[1][e] + geP[2][e] + geP[3][e];
      mx = fmaxf(mx, p[e]);
    }
#pragma unroll
    for (int e = 0; e < NEXP; e++) { p[e] = __expf(p[e] - mx); s += p[e]; }
    int e0 = 0; float b0 = p[0];
    for (int e = 1; e < NEXP; e++) if (p[e] > b0) { b0 = p[e]; e0 = e; }
    int e1 = -1; float b1v = -1.f;
    for (int e = 0; e < NEXP; e++) if (e != e0 && p[e] > b1v) { b1v = p[e]; e1 = e; }
    float inv = 1.f / s;
    int pos0 = atomicAdd(&counts[e0], 1);
    toklist[e0 * SEQ + pos0] = t;
    wtlist[e0 * SEQ + pos0] = fmaxf(b0 * inv, 1e-7f);
    int pos1 = atomicAdd(&counts[e1], 1);
    toklist[e1 * SEQ + pos1] = t;
    wtlist[e1 * SEQ + pos1] = fmaxf(b1v * inv, 1e-7f);
  }
}

// ---------------------------------------------------------------- GEMM1: fused SwiGLU, 10 experts
// 64x64 tile, BK=64 single-buffered, 8-chunk XOR swizzle. grid.x=16: panel pinned to one XCD.
__global__ __launch_bounds__(256) void gemm1_kernel(
    const u16* __restrict__ xfb,
    const u16* __restrict__ w1b, const u16* __restrict__ w3b, const u16* __restrict__ fc1b,
    const float* __restrict__ b1, const float* __restrict__ b3, const float* __restrict__ fc1_b,
    const int* __restrict__ counts, const int* __restrict__ toklist, u16* __restrict__ hb) {
  __shared__ u16 As[64][64];
  __shared__ u16 W1s[64][64];
  __shared__ u16 W3s[64][64];
  __shared__ int rIdx[64];
  const int e = blockIdx.z;
  const bool routed = (e < NEXP);
  int cnt, off;
  if (routed) {
    cnt = counts[e];
    off = 0;
    for (int i = 0; i < e; i++) off += counts[i];
  } else {
    cnt = SEQ;
    off = 2 * SEQ + (e - NEXP) * SEQ;
  }
  const int m0 = blockIdx.y * 64;
  if (m0 >= cnt) return;
  const int n0 = blockIdx.x * 64;
  const int tid = threadIdx.x;
  if (tid < 64) {
    int rr = m0 + tid;
    rIdx[tid] = routed ? toklist[e * SEQ + (rr < cnt ? rr : cnt - 1)] : rr;
  }
  __syncthreads();
  const u16* W1 = routed ? w1b + (size_t)e * IDIM * DMODEL
                         : fc1b + (size_t)(e - NEXP) * IDIM * DMODEL;
  const ptrdiff_t d31 = w3b - w1b;   // W3 row = W1 row + d31 (routed only)

  const int lane = tid & 63, w = tid >> 6;
  const int quad = lane >> 4, l15 = lane & 15;
  const int wy = w >> 1, wx = w & 1;
  const int lr8 = lane >> 3;                       // row within 8-row staging slab
  const int sch = ((lane & 7) ^ lr8) * 8;          // pre-swizzled source chunk (u16)

  const u16 *aS[2], *w1S[2];
#pragma unroll
  for (int c = 0; c < 2; c++) {
    int tr = 16 * w + 8 * c + lr8;
    aS[c]  = xfb + (size_t)rIdx[tr] * DMODEL + sch;
    w1S[c] = W1 + (size_t)(n0 + tr) * DMODEL + sch;
  }

  f32x4 acc1[2][2] = {};
  f32x4 acc3[2][2] = {};
  for (int k0 = 0; k0 < DMODEL; k0 += 64) {
#pragma unroll
    for (int c = 0; c < 2; c++) glds16(aS[c] + k0, &As[16 * w + 8 * c][0]);
#pragma unroll
    for (int c = 0; c < 2; c++) glds16(w1S[c] + k0, &W1s[16 * w + 8 * c][0]);
    if (routed) {
#pragma unroll
      for (int c = 0; c < 2; c++) glds16(w1S[c] + d31 + k0, &W3s[16 * w + 8 * c][0]);
    }
    __syncthreads();
#pragma unroll
    for (int kk = 0; kk < 2; kk++) {
      const int cb = (((kk * 4 + quad) ^ (l15 & 7))) * 8;
      s16x8 af[2], w1f[2];
#pragma unroll
      for (int i = 0; i < 2; i++) af[i] = *(const s16x8*)&As[32 * wy + 16 * i + l15][cb];
#pragma unroll
      for (int j = 0; j < 2; j++) w1f[j] = *(const s16x8*)&W1s[32 * wx + 16 * j + l15][cb];
#pragma unroll
      for (int i = 0; i < 2; i++)
#pragma unroll
        for (int j = 0; j < 2; j++)
          acc1[i][j] = MFMA_BF16(af[i], w1f[j], acc1[i][j]);
      if (routed) {
        s16x8 w3f[2];
#pragma unroll
        for (int j = 0; j < 2; j++) w3f[j] = *(const s16x8*)&W3s[32 * wx + 16 * j + l15][cb];
#pragma unroll
        for (int i = 0; i < 2; i++)
#pragma unroll
          for (int j = 0; j < 2; j++)
            acc3[i][j] = MFMA_BF16(af[i], w3f[j], acc3[i][j]);
      }
    }
    __syncthreads();
  }

#pragma unroll
  for (int j = 0; j < 2; j++) {
    int n = n0 + 32 * wx + 16 * j + l15;
    float b1v = routed ? b1[e * IDIM + n] : fc1_b[(e - NEXP) * IDIM + n];
    float b3v = routed ? b3[e * IDIM + n] : 0.f;
#pragma unroll
    for (int i = 0; i < 2; i++) {
#pragma unroll
      for (int r = 0; r < 4; r++) {
        int rr = m0 + 32 * wy + 16 * i + quad * 4 + r;
        if (rr < cnt) {
          float a = acc1[i][j][r] + b1v;
          float g = routed ? (acc3[i][j][r] + b3v) : 1.f;
          float hv = a / (1.f + __expf(-a)) * g;
          hb[(size_t)(off + rr) * IDIM + n] = f2b(hv);
        }
      }
    }
  }
}

// ---------------------------------------------------------------- GEMM2: down-proj, 10 experts
// 64x64 tile, BK=64 single-buffered, 8-chunk XOR swizzle (16KB).
// grid.x padded to 16 so blockid%8 = x%8 -> W2 panel pinned to one XCD; x>=12 exit.
__global__ __launch_bounds__(256) void gemm2_kernel(
    const u16* __restrict__ hb,
    const u16* __restrict__ w2b, const u16* __restrict__ fc2b,
    const float* __restrict__ b2, const float* __restrict__ fc2_b,
    const int* __restrict__ counts, const int* __restrict__ toklist,
    const float* __restrict__ wtlist, float* __restrict__ out) {
  __shared__ u16 As[64][64];
  __shared__ u16 Ws[64][64];
  const int n0 = blockIdx.x * 64;
  if (n0 >= DMODEL) return;
  const int e = blockIdx.z;
  const bool routed = (e < NEXP);
  int cnt, off;
  if (routed) {
    cnt = counts[e];
    off = 0;
    for (int i = 0; i < e; i++) off += counts[i];
  } else {
    cnt = SEQ;
    off = 2 * SEQ + (e - NEXP) * SEQ;
  }
  const int m0 = blockIdx.y * 64;
  if (m0 >= cnt) return;
  const int tid = threadIdx.x;

  const u16* Wb; int ldw, kof;
  if (routed) { Wb = w2b + (size_t)e * DMODEL * IDIM; ldw = IDIM; kof = 0; }
  else        { Wb = fc2b;                            ldw = ISH;  kof = (e - NEXP) * IDIM; }

  const int lane = tid & 63, w = tid >> 6;
  const int quad = lane >> 4, l15 = lane & 15;
  const int wy = w >> 1, wx = w & 1;
  const int lr8 = lane >> 3;
  const int sch = ((lane & 7) ^ lr8) * 8;

  const u16 *aS[2], *wS[2];
#pragma unroll
  for (int c = 0; c < 2; c++) {
    int tr = 16 * w + 8 * c + lr8;
    int ra = m0 + tr;
    ra = off + (ra < cnt ? ra : cnt - 1);
    aS[c] = hb + (size_t)ra * IDIM + sch;
    wS[c] = Wb + (size_t)(n0 + tr) * ldw + kof + sch;
  }

  f32x4 acc[2][2] = {};
  for (int k0 = 0; k0 < IDIM; k0 += 64) {
#pragma unroll
    for (int c = 0; c < 2; c++) glds16(aS[c] + k0, &As[16 * w + 8 * c][0]);
#pragma unroll
    for (int c = 0; c < 2; c++) glds16(wS[c] + k0, &Ws[16 * w + 8 * c][0]);
    __syncthreads();
#pragma unroll
    for (int kk = 0; kk < 2; kk++) {
      const int cb = (((kk * 4 + quad) ^ (l15 & 7))) * 8;
      s16x8 af[2], wf[2];
#pragma unroll
      for (int i = 0; i < 2; i++) af[i] = *(const s16x8*)&As[32 * wy + 16 * i + l15][cb];
#pragma unroll
      for (int j = 0; j < 2; j++) wf[j] = *(const s16x8*)&Ws[32 * wx + 16 * j + l15][cb];
#pragma unroll
      for (int i = 0; i < 2; i++)
#pragma unroll
        for (int j = 0; j < 2; j++)
          acc[i][j] = MFMA_BF16(af[i], wf[j], acc[i][j]);
    }
    __syncthreads();
  }

#pragma unroll
  for (int j = 0; j < 2; j++) {
    int n = n0 + 32 * wx + 16 * j + l15;
    float bv = routed ? b2[e * DMODEL + n] : (e == NEXP ? fc2_b[n] : 0.f);
#pragma unroll
    for (int i = 0; i < 2; i++) {
#pragma unroll
      for (int r = 0; r < 4; r++) {
        int rr = m0 + 32 * wy + 16 * i + quad * 4 + r;
        if (rr < cnt) {
          int tok; float wt;
          if (routed) { tok = toklist[e * SEQ + rr]; wt = wtlist[e * SEQ + rr]; }
          else        { tok = rr;                    wt = 1.f; }
          atomicAdd(&out[(size_t)tok * DMODEL + n], wt * (acc[i][j][r] + bv));
        }
      }
    }
  }
}

// ---------------------------------------------------------------- launch
extern "C" void kernel_launch(void* const* d_in, const int* in_sizes, int n_in,
                              void* d_out, int out_size, void* d_ws, size_t ws_size,
                              hipStream_t stream) {
  const float* x       = (const float*)d_in[0];
  const float* norm1_w = (const float*)d_in[1];
  const float* norm3_w = (const float*)d_in[2];
  const float* gate_w  = (const float*)d_in[3];
  const float* w1      = (const float*)d_in[4];
  const float* b1      = (const float*)d_in[5];
  const float* w2      = (const float*)d_in[6];
  const float* b2      = (const float*)d_in[7];
  const float* w3      = (const float*)d_in[8];
  const float* b3      = (const float*)d_in[9];
  const float* fc1_w   = (const float*)d_in[10];
  const float* fc1_b   = (const float*)d_in[11];
  const float* fc2_w   = (const float*)d_in[12];
  const float* fc2_b   = (const float*)d_in[13];
  float* out = (float*)d_out;

  // workspace layout
  char* p = (char*)d_ws;
  u16*   xnb    = (u16*)p;   p += (size_t)SEQ * DMODEL * 2;
  u16*   xfb    = (u16*)p;   p += (size_t)SEQ * DMODEL * 2;
  u16*   hb     = (u16*)p;   p += (size_t)4 * SEQ * IDIM * 2;        // 8192 slots
  u16*   Opart  = (u16*)p;   p += (size_t)KVS * NHEAD * SEQ * 64 * 2;
  float* Mpart  = (float*)p; p += (size_t)KVS * NHEAD * SEQ * 4;
  float* Lpart  = (float*)p; p += (size_t)KVS * NHEAD * SEQ * 4;
  u16*   w1b    = (u16*)p;   p += (size_t)NEXP * IDIM * DMODEL * 2;
  u16*   w3b    = (u16*)p;   p += (size_t)NEXP * IDIM * DMODEL * 2;
  u16*   w2b    = (u16*)p;   p += (size_t)NEXP * DMODEL * IDIM * 2;
  u16*   fc1b   = (u16*)p;   p += (size_t)ISH * DMODEL * 2;
  u16*   fc2b   = (u16*)p;   p += (size_t)DMODEL * ISH * 2;
  int*   counts = (int*)p;   p += 256;
  int*   toklist= (int*)p;   p += (size_t)NEXP * SEQ * 4;
  float* wtlist = (float*)p; p += (size_t)NEXP * SEQ * 4;

  rmsnorm_kernel<<<SEQ / 4, 256, 0, stream>>>(x, norm1_w, xnb, counts);
  attn_cvt_kernel<<<ATTN_BLOCKS + CVT_BLOCKS, 256, 0, stream>>>(
      xnb, Opart, Mpart, Lpart, w1, w3, w2, fc1_w, fc2_w,
      w1b, w3b, w2b, fc1b, fc2b);
  fused_post_kernel<<<SEQ, 256, 0, stream>>>(Opart, Mpart, Lpart, x, norm3_w, gate_w,
                                             xfb, out, counts, toklist, wtlist);
  gemm1_kernel<<<dim3(IDIM / 64, SEQ / 64, NE2), 256, 0, stream>>>(
      xfb, w1b, w3b, fc1b, b1, b3, fc1_b, counts, toklist, hb);
  gemm2_kernel<<<dim3(16, SEQ / 64, NE2), 256, 0, stream>>>(
      hb, w2b, fc2b, b2, fc2_b, counts, toklist, wtlist, out);
  (void)in_sizes; (void)n_in; (void)out_size; (void)ws_size;
}

// Round 12
// 311.045 us; speedup vs baseline: 1.0466x; 1.0080x over previous
//
#include <hip/hip_runtime.h>
#include <math.h>

#define SEQ    2048
#define DMODEL 768
#define NHEAD  12
#define NEXP   8
#define IDIM   1024
#define ISH    2048
#define KVS    4
#define NE2    10   // 8 routed experts + 2 shared-expert halves
#define ATTN_BLOCKS 1536    // 32 q-tiles * 12 heads * 4 kv-splits
#define CVT1_BLOCKS 3456    // (2*786432 + 196608) groups / 512 (2 groups/thread): w1,w3,fc1
#define QK_SCALE 0.18033688011112042f  // 0.125 * log2(e): softmax runs in exp2 domain

typedef unsigned short u16;
typedef short s16x8 __attribute__((ext_vector_type(8)));
typedef u16   u16x8 __attribute__((ext_vector_type(8)));
typedef float f32x4 __attribute__((ext_vector_type(4)));

#define MFMA_BF16(a, b, c) __builtin_amdgcn_mfma_f32_16x16x32_bf16((a), (b), (c), 0, 0, 0)

__device__ __forceinline__ void glds16(const void* g, void* l) {
  __builtin_amdgcn_global_load_lds(
      (const __attribute__((address_space(1))) unsigned int*)g,
      (__attribute__((address_space(3))) unsigned int*)l, 16, 0, 0);
}

__device__ __forceinline__ u16 f2b(float f) {  // fp32 -> bf16 RNE
  unsigned int u = __float_as_uint(f);
  unsigned int r = u + 0x7fffu + ((u >> 16) & 1u);
  return (u16)(r >> 16);
}
__device__ __forceinline__ float b2f(u16 v) {
  return __uint_as_float(((unsigned int)v) << 16);
}

__device__ __forceinline__ void cvt8(const float* s, u16* d, long o) {
  float4 a = ((const float4*)s)[2 * o], b = ((const float4*)s)[2 * o + 1];
  u16x8 v;
  v[0] = f2b(a.x); v[1] = f2b(a.y); v[2] = f2b(a.z); v[3] = f2b(a.w);
  v[4] = f2b(b.x); v[5] = f2b(b.y); v[6] = f2b(b.z); v[7] = f2b(b.w);
  ((u16x8*)d)[o] = v;
}

// ---------------------------------------------------------------- rmsnorm1 (+ zero counts)
// Wave per row (4 rows/block), shuffle-only reductions, no barriers.
__global__ __launch_bounds__(256) void rmsnorm_kernel(const float* __restrict__ x,
                                                      const float* __restrict__ n1w,
                                                      u16* __restrict__ xnb,
                                                      int* __restrict__ counts) {
  const int tid = threadIdx.x;
  if (blockIdx.x == 0 && tid < 16) counts[tid] = 0;
  const int lane = tid & 63, w = tid >> 6;
  const int row = blockIdx.x * 4 + w;
  const float* r = x + (size_t)row * DMODEL;
  float v[12];
  float ss = 0.f;
#pragma unroll
  for (int i = 0; i < 12; i++) { v[i] = r[i * 64 + lane]; ss += v[i] * v[i]; }
#pragma unroll
  for (int off = 32; off >= 1; off >>= 1) ss += __shfl_xor(ss, off, 64);
  float rms = rsqrtf(ss * (1.f / DMODEL) + 1e-5f);
  u16* ob = xnb + (size_t)row * DMODEL;
#pragma unroll
  for (int i = 0; i < 12; i++) ob[i * 64 + lane] = f2b(v[i] * rms * n1w[i * 64 + lane]);
}

// ---------------------------------------------------------------- merged: MFMA flash attention
// (blocks [0,ATTN_BLOCKS)) + w1/w3/fc1 conversion (blocks after; w2/fc2 moved to gemm1 phase).
// LDS: QP + Ks[2] (double-buffered K prefetch) + Vt = 32KB. Softmax in exp2 domain.
__global__ __launch_bounds__(256) void attn_cvt_kernel(
    const u16* __restrict__ xnb, u16* __restrict__ Opart,
    float* __restrict__ Mpart, float* __restrict__ Lpart,
    const float* __restrict__ w1, const float* __restrict__ w3, const float* __restrict__ fc1,
    u16* __restrict__ w1b, u16* __restrict__ w3b, u16* __restrict__ fc1b) {
  const int tid = threadIdx.x;
  if (blockIdx.x >= ATTN_BLOCKS) {
    // ---- weight cvt: w1, w3, fc1 (2 groups of 8 floats per thread) ----
    long i0 = (long)(blockIdx.x - ATTN_BLOCKS) * 512 + tid * 2;
    const long NW8 = (long)NEXP * IDIM * DMODEL / 8;   // 786432
    const float* s; u16* d; long o;
    if      (i0 < NW8)      { s = w1;  d = w1b;  o = i0; }
    else if (i0 < 2 * NW8)  { s = w3;  d = w3b;  o = i0 - NW8; }
    else                    { s = fc1; d = fc1b; o = i0 - 2 * NW8; }
    cvt8(s, d, o);
    cvt8(s, d, o + 1);   // array boundaries are even: pair never straddles
    return;
  }
  // ---- attention ----
  __shared__ u16 QP[64][64];      // Qs before the loop; Ps inside (Qs dead after frag hoist)
  __shared__ u16 Ks[2][64][64];   // double-buffered; slot (r,c) holds chunk c ^ ((r>>1)&7)
  __shared__ u16 Vt[64][64];      // transposed V: [d][k], same swizzle
  const int q0 = (blockIdx.x & 31) * 64;
  const int h = (blockIdx.x >> 5) % NHEAD;
  const int kvs = blockIdx.x / (32 * NHEAD);
  const int lane = tid & 63, w = tid >> 6;
  const int quad = lane >> 4, l15 = lane & 15;
  const size_t hoff = (size_t)h * 64;

  const int lr8 = lane >> 3, b7 = lane & 7;
  const int sch0 = (b7 ^ (lr8 >> 1)) * 8;
  const int sch1 = (b7 ^ (4 + (lr8 >> 1))) * 8;
  const int rkey = (l15 >> 1) & 7;           // fragment read key for row (16*jt + l15)
  const int cb0 = (quad ^ rkey) * 8;         // global chunk quad
  const int cb1 = ((4 + quad) ^ rkey) * 8;   // global chunk 4+quad

  const int it0 = kvs * (SEQ / 64 / KVS);
  const int NIT = SEQ / 64 / KVS;            // 8

  glds16(xnb + (size_t)(q0 + 16 * w + lr8) * DMODEL + hoff + sch0, &QP[16 * w][0]);
  glds16(xnb + (size_t)(q0 + 16 * w + 8 + lr8) * DMODEL + hoff + sch1, &QP[16 * w + 8][0]);
  {
    const int k0 = it0 * 64;
    glds16(xnb + (size_t)(k0 + 16 * w + lr8) * DMODEL + hoff + sch0, &Ks[0][16 * w][0]);
    glds16(xnb + (size_t)(k0 + 16 * w + 8 + lr8) * DMODEL + hoff + sch1, &Ks[0][16 * w + 8][0]);
  }
  __syncthreads();
  const s16x8 aq0 = *(const s16x8*)&QP[16 * w + l15][cb0];
  const s16x8 aq1 = *(const s16x8*)&QP[16 * w + l15][cb1];

  f32x4 o[4] = {};
  float mrow[4], lrow[4];
#pragma unroll
  for (int r = 0; r < 4; r++) { mrow[r] = -INFINITY; lrow[r] = 0.f; }

  int cur = 0;
  for (int it = 0; it < NIT; it++) {
    __syncthreads();   // drains prefetch vmcnt + prior-iter LDS reads of Ks[cur]/QP/Vt

    if (it + 1 < NIT) {   // prefetch next K-tile into the idle buffer
      const int kn = (it0 + it + 1) * 64;
      glds16(xnb + (size_t)(kn + 16 * w + lr8) * DMODEL + hoff + sch0,
             &Ks[cur ^ 1][16 * w][0]);
      glds16(xnb + (size_t)(kn + 16 * w + 8 + lr8) * DMODEL + hoff + sch1,
             &Ks[cur ^ 1][16 * w + 8][0]);
    }

    {
      // transpose K -> Vt; Ks rows 2rp,2rp+1 share key rp&7; Vt rows wave-private
      const int rp = tid & 31, dcc = (tid >> 5) & 7;
      const int tc = (dcc ^ (rp & 7)) * 8;
      u16x8 v0 = *(const u16x8*)&Ks[cur][2 * rp][tc];
      u16x8 v1 = *(const u16x8*)&Ks[cur][2 * rp + 1][tc];
#pragma unroll
      for (int j = 0; j < 8; j++) {
        const int vrow = dcc * 8 + j;
        const int vkey = (vrow >> 1) & 7;
        *(unsigned int*)&Vt[vrow][((rp >> 2) ^ vkey) * 8 + (rp & 3) * 2] =
            (unsigned int)v0[j] | ((unsigned int)v1[j] << 16);
      }
    }

    f32x4 s4[4] = {};
    __builtin_amdgcn_s_setprio(1);
#pragma unroll
    for (int jt = 0; jt < 4; jt++) {
      s16x8 b0 = *(const s16x8*)&Ks[cur][16 * jt + l15][cb0];
      s16x8 b1 = *(const s16x8*)&Ks[cur][16 * jt + l15][cb1];
      s4[jt] = MFMA_BF16(aq0, b0, s4[jt]);
      s4[jt] = MFMA_BF16(aq1, b1, s4[jt]);
      s4[jt] *= QK_SCALE;   // exp2 domain
    }
    __builtin_amdgcn_s_setprio(0);

#pragma unroll
    for (int r = 0; r < 4; r++) {
      float mx = mrow[r];
#pragma unroll
      for (int jt = 0; jt < 4; jt++) mx = fmaxf(mx, s4[jt][r]);
#pragma unroll
      for (int m = 1; m <= 8; m <<= 1) mx = fmaxf(mx, __shfl_xor(mx, m, 64));
      float al = exp2f(mrow[r] - mx);
      mrow[r] = mx;
      float pv[4], sum = 0.f;
#pragma unroll
      for (int jt = 0; jt < 4; jt++) { pv[jt] = exp2f(s4[jt][r] - mx); sum += pv[jt]; }
#pragma unroll
      for (int m = 1; m <= 8; m <<= 1) sum += __shfl_xor(sum, m, 64);
      lrow[r] = lrow[r] * al + sum;
#pragma unroll
      for (int jt = 0; jt < 4; jt++) o[jt][r] *= al;
      const int pkey = ((quad * 4 + r) >> 1) & 7;   // key of row 16w+quad*4+r (wave-private)
#pragma unroll
      for (int jt = 0; jt < 4; jt++)
        QP[16 * w + quad * 4 + r][((2 * jt + (l15 >> 3)) ^ pkey) * 8 + (l15 & 7)] =
            f2b(pv[jt]);
    }
    __syncthreads();

    s16x8 ap0 = *(const s16x8*)&QP[16 * w + l15][cb0];
    s16x8 ap1 = *(const s16x8*)&QP[16 * w + l15][cb1];
    __builtin_amdgcn_s_setprio(1);
#pragma unroll
    for (int jt = 0; jt < 4; jt++) {
      s16x8 bv0 = *(const s16x8*)&Vt[16 * jt + l15][cb0];
      s16x8 bv1 = *(const s16x8*)&Vt[16 * jt + l15][cb1];
      o[jt] = MFMA_BF16(ap0, bv0, o[jt]);
      o[jt] = MFMA_BF16(ap1, bv1, o[jt]);
    }
    __builtin_amdgcn_s_setprio(0);
    cur ^= 1;
  }

  const int hk = h * KVS + kvs;
#pragma unroll
  for (int r = 0; r < 4; r++) {
    int q = q0 + 16 * w + quad * 4 + r;
    size_t base = (size_t)q * (KVS * NHEAD) + hk;
#pragma unroll
    for (int jt = 0; jt < 4; jt++)
      Opart[base * 64 + 16 * jt + l15] = f2b(o[jt][r]);
    if (l15 == 0) {
      Mpart[base] = mrow[r];
      Lpart[base] = lrow[r];
    }
  }
}

// ---------------------------------------------------------------- fused post-attention
// Block per token, 4 waves (wave w owns heads 3w..3w+2), 2 barriers. M/L in exp2 domain.
__global__ __launch_bounds__(256) void fused_post_kernel(
    const u16* __restrict__ Opart, const float* __restrict__ Mpart,
    const float* __restrict__ Lpart, const float* __restrict__ x,
    const float* __restrict__ n3w, const float* __restrict__ gw,
    u16* __restrict__ xfb, float* __restrict__ out,
    int* __restrict__ counts, int* __restrict__ toklist, float* __restrict__ wtlist) {
  const int t = blockIdx.x;
  const int tid = threadIdx.x;
  const int lane = tid & 63, w = tid >> 6;
  __shared__ u16 Os[48 * 64];     // 6KB staged Opart row
  __shared__ float MsLs[96];      // [0,48): M, [48,96): L
  __shared__ float ssP[4];
  __shared__ float geP[4][NEXP];

  const u16* orow = Opart + (size_t)t * (48 * 64);
  for (int c = tid; c < 384; c += 256)
    *(u16x8*)&Os[c * 8] = *(const u16x8*)&orow[c * 8];
  if (tid < 96)
    MsLs[tid] = (tid < 48) ? Mpart[(size_t)t * 48 + tid]
                           : Lpart[(size_t)t * 48 + (tid - 48)];
  __syncthreads();

  float val[3];
  float ss = 0.f;
  const float* xr = x + (size_t)t * DMODEL;
  float* outr = out + (size_t)t * DMODEL;
#pragma unroll
  for (int j = 0; j < 3; j++) {
    const int ii = 3 * w + j;
    float m0 = MsLs[ii * 4 + 0], m1 = MsLs[ii * 4 + 1];
    float m2 = MsLs[ii * 4 + 2], m3 = MsLs[ii * 4 + 3];
    float mh = fmaxf(fmaxf(m0, m1), fmaxf(m2, m3));
    float c0 = exp2f(m0 - mh), c1 = exp2f(m1 - mh);
    float c2 = exp2f(m2 - mh), c3 = exp2f(m3 - mh);
    float Lh = c0 * MsLs[48 + ii * 4 + 0] + c1 * MsLs[48 + ii * 4 + 1] +
               c2 * MsLs[48 + ii * 4 + 2] + c3 * MsLs[48 + ii * 4 + 3];
    float O = c0 * b2f(Os[(ii * 4 + 0) * 64 + lane]) +
              c1 * b2f(Os[(ii * 4 + 1) * 64 + lane]) +
              c2 * b2f(Os[(ii * 4 + 2) * 64 + lane]) +
              c3 * b2f(Os[(ii * 4 + 3) * 64 + lane]);
    float v = xr[ii * 64 + lane] + O / Lh;
    outr[ii * 64 + lane] = v;
    val[j] = v;
    ss += v * v;
  }
#pragma unroll
  for (int off = 32; off >= 1; off >>= 1) ss += __shfl_xor(ss, off, 64);
  if (lane == 0) ssP[w] = ss;
  __syncthreads();
  float rms = rsqrtf((ssP[0] + ssP[1] + ssP[2] + ssP[3]) * (1.f / DMODEL) + 1e-5f);

  float ge[NEXP] = {};
#pragma unroll
  for (int j = 0; j < 3; j++) {
    int c = (3 * w + j) * 64 + lane;
    float xn = val[j] * rms * n3w[c];
    xfb[(size_t)t * DMODEL + c] = f2b(xn);
#pragma unroll
    for (int e = 0; e < NEXP; e++) ge[e] = fmaf(xn, gw[e * DMODEL + c], ge[e]);
  }
#pragma unroll
  for (int off = 32; off >= 1; off >>= 1)
#pragma unroll
    for (int e = 0; e < NEXP; e++) ge[e] += __shfl_xor(ge[e], off, 64);
  if (lane == 0)
#pragma unroll
    for (int e = 0; e < NEXP; e++) geP[w][e] = ge[e];
  __syncthreads();

  if (tid == 0) {
    float p[NEXP], mx = -INFINITY, s = 0.f;
#pragma unroll
    for (int e = 0; e < NEXP; e++) {
      p[e] = geP[0][e] + geP[1][e] + geP[2][e] + geP[3][e];
      mx = fmaxf(mx, p[e]);
    }
#pragma unroll
    for (int e = 0; e < NEXP; e++) { p[e] = __expf(p[e] - mx); s += p[e]; }
    int e0 = 0; float b0 = p[0];
    for (int e = 1; e < NEXP; e++) if (p[e] > b0) { b0 = p[e]; e0 = e; }
    int e1 = -1; float b1v = -1.f;
    for (int e = 0; e < NEXP; e++) if (e != e0 && p[e] > b1v) { b1v = p[e]; e1 = e; }
    float inv = 1.f / s;
    int pos0 = atomicAdd(&counts[e0], 1);
    toklist[e0 * SEQ + pos0] = t;
    wtlist[e0 * SEQ + pos0] = fmaxf(b0 * inv, 1e-7f);
    int pos1 = atomicAdd(&counts[e1], 1);
    toklist[e1 * SEQ + pos1] = t;
    wtlist[e1 * SEQ + pos1] = fmaxf(b1v * inv, 1e-7f);
  }
}

// ---------------------------------------------------------------- GEMM1: fused SwiGLU, 10 experts
// 64x64 tile, BK=64 single-buffered, 8-chunk XOR swizzle. grid.x=16: panel pinned to one XCD.
// z >= NE2: w2/fc2 bf16 conversion tail (overlaps gemm1 drain; completes before gemm2).
__global__ __launch_bounds__(256) void gemm1_kernel(
    const u16* __restrict__ xfb,
    const u16* __restrict__ w1b, const u16* __restrict__ w3b, const u16* __restrict__ fc1b,
    const float* __restrict__ b1, const float* __restrict__ b3, const float* __restrict__ fc1_b,
    const int* __restrict__ counts, const int* __restrict__ toklist, u16* __restrict__ hb,
    const float* __restrict__ w2f, const float* __restrict__ fc2f,
    u16* __restrict__ w2b, u16* __restrict__ fc2b) {
  const int tid = threadIdx.x;
  if (blockIdx.z >= NE2) {
    // ---- weight cvt: w2, fc2 ----
    long i = ((long)(blockIdx.z - NE2) * 512 + blockIdx.y * 16 + blockIdx.x) * 256 + tid;
    const long NW8 = (long)NEXP * IDIM * DMODEL / 8;   // 786432
    const long NF8 = (long)ISH * DMODEL / 8;           // 196608
    if (i >= NW8 + NF8) return;
    if (i < NW8) cvt8(w2f, w2b, i);
    else         cvt8(fc2f, fc2b, i - NW8);
    return;
  }
  __shared__ u16 As[64][64];
  __shared__ u16 W1s[64][64];
  __shared__ u16 W3s[64][64];
  __shared__ int rIdx[64];
  const int e = blockIdx.z;
  const bool routed = (e < NEXP);
  int cnt, off;
  if (routed) {
    cnt = counts[e];
    off = 0;
    for (int i = 0; i < e; i++) off += counts[i];
  } else {
    cnt = SEQ;
    off = 2 * SEQ + (e - NEXP) * SEQ;
  }
  const int m0 = blockIdx.y * 64;
  if (m0 >= cnt) return;
  const int n0 = blockIdx.x * 64;
  if (tid < 64) {
    int rr = m0 + tid;
    rIdx[tid] = routed ? toklist[e * SEQ + (rr < cnt ? rr : cnt - 1)] : rr;
  }
  __syncthreads();
  const u16* W1 = routed ? w1b + (size_t)e * IDIM * DMODEL
                         : fc1b + (size_t)(e - NEXP) * IDIM * DMODEL;
  const ptrdiff_t d31 = w3b - w1b;   // W3 row = W1 row + d31 (routed only)

  const int lane = tid & 63, w = tid >> 6;
  const int quad = lane >> 4, l15 = lane & 15;
  const int wy = w >> 1, wx = w & 1;
  const int lr8 = lane >> 3;                       // row within 8-row staging slab
  const int sch = ((lane & 7) ^ lr8) * 8;          // pre-swizzled source chunk (u16)

  const u16 *aS[2], *w1S[2];
#pragma unroll
  for (int c = 0; c < 2; c++) {
    int tr = 16 * w + 8 * c + lr8;
    aS[c]  = xfb + (size_t)rIdx[tr] * DMODEL + sch;
    w1S[c] = W1 + (size_t)(n0 + tr) * DMODEL + sch;
  }

  f32x4 acc1[2][2] = {};
  f32x4 acc3[2][2] = {};
  for (int k0 = 0; k0 < DMODEL; k0 += 64) {
#pragma unroll
    for (int c = 0; c < 2; c++) glds16(aS[c] + k0, &As[16 * w + 8 * c][0]);
#pragma unroll
    for (int c = 0; c < 2; c++) glds16(w1S[c] + k0, &W1s[16 * w + 8 * c][0]);
    if (routed) {
#pragma unroll
      for (int c = 0; c < 2; c++) glds16(w1S[c] + d31 + k0, &W3s[16 * w + 8 * c][0]);
    }
    __syncthreads();
#pragma unroll
    for (int kk = 0; kk < 2; kk++) {
      const int cb = (((kk * 4 + quad) ^ (l15 & 7))) * 8;
      s16x8 af[2], w1f[2];
#pragma unroll
      for (int i = 0; i < 2; i++) af[i] = *(const s16x8*)&As[32 * wy + 16 * i + l15][cb];
#pragma unroll
      for (int j = 0; j < 2; j++) w1f[j] = *(const s16x8*)&W1s[32 * wx + 16 * j + l15][cb];
#pragma unroll
      for (int i = 0; i < 2; i++)
#pragma unroll
        for (int j = 0; j < 2; j++)
          acc1[i][j] = MFMA_BF16(af[i], w1f[j], acc1[i][j]);
      if (routed) {
        s16x8 w3f[2];
#pragma unroll
        for (int j = 0; j < 2; j++) w3f[j] = *(const s16x8*)&W3s[32 * wx + 16 * j + l15][cb];
#pragma unroll
        for (int i = 0; i < 2; i++)
#pragma unroll
          for (int j = 0; j < 2; j++)
            acc3[i][j] = MFMA_BF16(af[i], w3f[j], acc3[i][j]);
      }
    }
    __syncthreads();
  }

#pragma unroll
  for (int j = 0; j < 2; j++) {
    int n = n0 + 32 * wx + 16 * j + l15;
    float b1v = routed ? b1[e * IDIM + n] : fc1_b[(e - NEXP) * IDIM + n];
    float b3v = routed ? b3[e * IDIM + n] : 0.f;
#pragma unroll
    for (int i = 0; i < 2; i++) {
#pragma unroll
      for (int r = 0; r < 4; r++) {
        int rr = m0 + 32 * wy + 16 * i + quad * 4 + r;
        if (rr < cnt) {
          float a = acc1[i][j][r] + b1v;
          float g = routed ? (acc3[i][j][r] + b3v) : 1.f;
          float hv = a / (1.f + __expf(-a)) * g;
          hb[(size_t)(off + rr) * IDIM + n] = f2b(hv);
        }
      }
    }
  }
}

// ---------------------------------------------------------------- GEMM2: down-proj, 10 experts
// 64x64 tile, BK=64 single-buffered, 8-chunk XOR swizzle (16KB).
// grid.x padded to 16 so blockid%8 = x%8 -> W2 panel pinned to one XCD; x>=12 exit.
__global__ __launch_bounds__(256) void gemm2_kernel(
    const u16* __restrict__ hb,
    const u16* __restrict__ w2b, const u16* __restrict__ fc2b,
    const float* __restrict__ b2, const float* __restrict__ fc2_b,
    const int* __restrict__ counts, const int* __restrict__ toklist,
    const float* __restrict__ wtlist, float* __restrict__ out) {
  __shared__ u16 As[64][64];
  __shared__ u16 Ws[64][64];
  const int n0 = blockIdx.x * 64;
  if (n0 >= DMODEL) return;
  const int e = blockIdx.z;
  const bool routed = (e < NEXP);
  int cnt, off;
  if (routed) {
    cnt = counts[e];
    off = 0;
    for (int i = 0; i < e; i++) off += counts[i];
  } else {
    cnt = SEQ;
    off = 2 * SEQ + (e - NEXP) * SEQ;
  }
  const int m0 = blockIdx.y * 64;
  if (m0 >= cnt) return;
  const int tid = threadIdx.x;

  const u16* Wb; int ldw, kof;
  if (routed) { Wb = w2b + (size_t)e * DMODEL * IDIM; ldw = IDIM; kof = 0; }
  else        { Wb = fc2b;                            ldw = ISH;  kof = (e - NEXP) * IDIM; }

  const int lane = tid & 63, w = tid >> 6;
  const int quad = lane >> 4, l15 = lane & 15;
  const int wy = w >> 1, wx = w & 1;
  const int lr8 = lane >> 3;
  const int sch = ((lane & 7) ^ lr8) * 8;

  const u16 *aS[2], *wS[2];
#pragma unroll
  for (int c = 0; c < 2; c++) {
    int tr = 16 * w + 8 * c + lr8;
    int ra = m0 + tr;
    ra = off + (ra < cnt ? ra : cnt - 1);
    aS[c] = hb + (size_t)ra * IDIM + sch;
    wS[c] = Wb + (size_t)(n0 + tr) * ldw + kof + sch;
  }

  f32x4 acc[2][2] = {};
  for (int k0 = 0; k0 < IDIM; k0 += 64) {
#pragma unroll
    for (int c = 0; c < 2; c++) glds16(aS[c] + k0, &As[16 * w + 8 * c][0]);
#pragma unroll
    for (int c = 0; c < 2; c++) glds16(wS[c] + k0, &Ws[16 * w + 8 * c][0]);
    __syncthreads();
#pragma unroll
    for (int kk = 0; kk < 2; kk++) {
      const int cb = (((kk * 4 + quad) ^ (l15 & 7))) * 8;
      s16x8 af[2], wf[2];
#pragma unroll
      for (int i = 0; i < 2; i++) af[i] = *(const s16x8*)&As[32 * wy + 16 * i + l15][cb];
#pragma unroll
      for (int j = 0; j < 2; j++) wf[j] = *(const s16x8*)&Ws[32 * wx + 16 * j + l15][cb];
#pragma unroll
      for (int i = 0; i < 2; i++)
#pragma unroll
        for (int j = 0; j < 2; j++)
          acc[i][j] = MFMA_BF16(af[i], wf[j], acc[i][j]);
    }
    __syncthreads();
  }

#pragma unroll
  for (int j = 0; j < 2; j++) {
    int n = n0 + 32 * wx + 16 * j + l15;
    float bv = routed ? b2[e * DMODEL + n] : (e == NEXP ? fc2_b[n] : 0.f);
#pragma unroll
    for (int i = 0; i < 2; i++) {
#pragma unroll
      for (int r = 0; r < 4; r++) {
        int rr = m0 + 32 * wy + 16 * i + quad * 4 + r;
        if (rr < cnt) {
          int tok; float wt;
          if (routed) { tok = toklist[e * SEQ + rr]; wt = wtlist[e * SEQ + rr]; }
          else        { tok = rr;                    wt = 1.f; }
          atomicAdd(&out[(size_t)tok * DMODEL + n], wt * (acc[i][j][r] + bv));
        }
      }
    }
  }
}

// ---------------------------------------------------------------- launch
extern "C" void kernel_launch(void* const* d_in, const int* in_sizes, int n_in,
                              void* d_out, int out_size, void* d_ws, size_t ws_size,
                              hipStream_t stream) {
  const float* x       = (const float*)d_in[0];
  const float* norm1_w = (const float*)d_in[1];
  const float* norm3_w = (const float*)d_in[2];
  const float* gate_w  = (const float*)d_in[3];
  const float* w1      = (const float*)d_in[4];
  const float* b1      = (const float*)d_in[5];
  const float* w2      = (const float*)d_in[6];
  const float* b2      = (const float*)d_in[7];
  const float* w3      = (const float*)d_in[8];
  const float* b3      = (const float*)d_in[9];
  const float* fc1_w   = (const float*)d_in[10];
  const float* fc1_b   = (const float*)d_in[11];
  const float* fc2_w   = (const float*)d_in[12];
  const float* fc2_b   = (const float*)d_in[13];
  float* out = (float*)d_out;

  // workspace layout
  char* p = (char*)d_ws;
  u16*   xnb    = (u16*)p;   p += (size_t)SEQ * DMODEL * 2;
  u16*   xfb    = (u16*)p;   p += (size_t)SEQ * DMODEL * 2;
  u16*   hb     = (u16*)p;   p += (size_t)4 * SEQ * IDIM * 2;        // 8192 slots
  u16*   Opart  = (u16*)p;   p += (size_t)KVS * NHEAD * SEQ * 64 * 2;
  float* Mpart  = (float*)p; p += (size_t)KVS * NHEAD * SEQ * 4;
  float* Lpart  = (float*)p; p += (size_t)KVS * NHEAD * SEQ * 4;
  u16*   w1b    = (u16*)p;   p += (size_t)NEXP * IDIM * DMODEL * 2;
  u16*   w3b    = (u16*)p;   p += (size_t)NEXP * IDIM * DMODEL * 2;
  u16*   w2b    = (u16*)p;   p += (size_t)NEXP * DMODEL * IDIM * 2;
  u16*   fc1b   = (u16*)p;   p += (size_t)ISH * DMODEL * 2;
  u16*   fc2b   = (u16*)p;   p += (size_t)DMODEL * ISH * 2;
  int*   counts = (int*)p;   p += 256;
  int*   toklist= (int*)p;   p += (size_t)NEXP * SEQ * 4;
  float* wtlist = (float*)p; p += (size_t)NEXP * SEQ * 4;

  rmsnorm_kernel<<<SEQ / 4, 256, 0, stream>>>(x, norm1_w, xnb, counts);
  attn_cvt_kernel<<<ATTN_BLOCKS + CVT1_BLOCKS, 256, 0, stream>>>(
      xnb, Opart, Mpart, Lpart, w1, w3, fc1_w, w1b, w3b, fc1b);
  fused_post_kernel<<<SEQ, 256, 0, stream>>>(Opart, Mpart, Lpart, x, norm3_w, gate_w,
                                             xfb, out, counts, toklist, wtlist);
  gemm1_kernel<<<dim3(IDIM / 64, SEQ / 64, NE2 + 8), 256, 0, stream>>>(
      xfb, w1b, w3b, fc1b, b1, b3, fc1_b, counts, toklist, hb,
      w2, fc2_w, w2b, fc2b);
  gemm2_kernel<<<dim3(16, SEQ / 64, NE2), 256, 0, stream>>>(
      hb, w2b, fc2b, b2, fc2_b, counts, toklist, wtlist, out);
  (void)in_sizes; (void)n_in; (void)out_size; (void)ws_size;
}